// Round 1
// baseline (125.981 us; speedup 1.0000x reference)
//
#include <hip/hip_runtime.h>
#include <math.h>

#define NJ 64      // MAX_JETS
#define NB 128     // BATCH
#define ND 128     // HIDDEN

// workspace layout (float offsets)
#define WS_GPART 0                        // 128 chunks * 16384 = 2097152
#define WS_G     2097152                  // 16384
#define WS_T     (WS_G + 16384)           // 128
#define WS_P     (WS_T + 128)             // 128*64*64 = 524288 (scaled P)
#define WS_V     (WS_P + 524288)          // 128*64 = 8192
#define WS_SPART (WS_V + 8192)            // 128*16*2 = 4096
#define WS_STAT  (WS_SPART + 4096)        // 128*2 = 256

// ---------------------------------------------------------------------------
// Kernel 1: partial gram  Gpart[c] = A_c * A_c^T  over K-chunk c (128 cols)
// A = W viewed as (128, 16384). Block (c, half) computes rows [half*64,+64).
// ---------------------------------------------------------------------------
__global__ __launch_bounds__(256) void k_gpart(const float* __restrict__ W,
                                               float* __restrict__ gpart) {
    __shared__ float As[128 * 128];   // [k][n] transposed tile (64 KiB)
    const int chunk = blockIdx.x;     // 0..127
    const int half  = blockIdx.y;     // 0..1
    const int t = threadIdx.x;

    // load tile transposed: As[k][n] = W[n*16384 + chunk*128 + k]
    #pragma unroll
    for (int rep = 0; rep < 16; ++rep) {
        int linear = rep * 1024 + t * 4;
        int n  = linear >> 7;
        int k0 = linear & 127;
        float4 w4 = *reinterpret_cast<const float4*>(
            W + (size_t)n * 16384 + chunk * 128 + k0);
        As[(k0 + 0) * 128 + n] = w4.x;
        As[(k0 + 1) * 128 + n] = w4.y;
        As[(k0 + 2) * 128 + n] = w4.z;
        As[(k0 + 3) * 128 + n] = w4.w;
    }
    __syncthreads();

    const int tx = t & 15, ty = t >> 4;
    const int row0 = half * 64 + ty * 4;   // 4 rows
    const int col0 = tx * 8;               // 8 cols
    float acc[4][8];
    #pragma unroll
    for (int i = 0; i < 4; ++i)
        #pragma unroll
        for (int j = 0; j < 8; ++j) acc[i][j] = 0.f;

    for (int k = 0; k < 128; ++k) {
        float4 a  = *reinterpret_cast<const float4*>(&As[k * 128 + row0]);
        float4 b0 = *reinterpret_cast<const float4*>(&As[k * 128 + col0]);
        float4 b1 = *reinterpret_cast<const float4*>(&As[k * 128 + col0 + 4]);
        const float av[4] = {a.x, a.y, a.z, a.w};
        const float bv[8] = {b0.x, b0.y, b0.z, b0.w, b1.x, b1.y, b1.z, b1.w};
        #pragma unroll
        for (int i = 0; i < 4; ++i)
            #pragma unroll
            for (int j = 0; j < 8; ++j) acc[i][j] += av[i] * bv[j];
    }

    float* gp = gpart + (size_t)chunk * 16384;
    #pragma unroll
    for (int i = 0; i < 4; ++i) {
        float4 o0 = make_float4(acc[i][0], acc[i][1], acc[i][2], acc[i][3]);
        float4 o1 = make_float4(acc[i][4], acc[i][5], acc[i][6], acc[i][7]);
        *reinterpret_cast<float4*>(gp + (row0 + i) * 128 + col0)     = o0;
        *reinterpret_cast<float4*>(gp + (row0 + i) * 128 + col0 + 4) = o1;
    }
}

// ---------------------------------------------------------------------------
// Kernel 2: reduce partials -> G, and compute trace vector t
// ---------------------------------------------------------------------------
__global__ __launch_bounds__(256) void k_greduce(const float* __restrict__ gpart,
                                                 const float* __restrict__ W,
                                                 float* __restrict__ G,
                                                 float* __restrict__ tvec) {
    const int o = blockIdx.x * 256 + threadIdx.x;   // 0..16383
    float s = 0.f;
    for (int c = 0; c < 128; ++c) s += gpart[(size_t)c * 16384 + o];
    G[o] = s;
    if (blockIdx.x == 0 && threadIdx.x < 128) {
        float ts = 0.f;
        for (int a = 0; a < 128; ++a)
            ts += W[(size_t)threadIdx.x * 16384 + a * 129];
        tvec[threadIdx.x] = ts;
    }
}

// ---------------------------------------------------------------------------
// Kernel 3: per-batch  Y = X_b G ;  P_b = (Y X_b^T) * scale ;  v_b = X_b t
// Block (b, half): computes 32 rows of Y/P. LDS <= 52 KiB.
// ---------------------------------------------------------------------------
__global__ __launch_bounds__(256) void k_pv(const float* __restrict__ x,
                                            const float* __restrict__ G,
                                            const float* __restrict__ tvec,
                                            float* __restrict__ P,
                                            float* __restrict__ V) {
    __shared__ float XsT[128 * 68];   // [i][n], n padded to 68
    __shared__ float buf[32 * 132];   // G chunk [32][132], later Ys [32][132]
    __shared__ float ts[128];
    const int b    = blockIdx.x;      // 0..127
    const int half = blockIdx.y;      // 0..1
    const int t = threadIdx.x;

    // X_b transposed into LDS: XsT[i][n] = x[n*16384 + b*128 + i]
    #pragma unroll
    for (int rep = 0; rep < 8; ++rep) {
        int linear = rep * 1024 + t * 4;   // 0..8191
        int n  = linear >> 7;
        int i0 = linear & 127;
        float4 x4 = *reinterpret_cast<const float4*>(
            x + (size_t)n * 16384 + b * 128 + i0);
        XsT[(i0 + 0) * 68 + n] = x4.x;
        XsT[(i0 + 1) * 68 + n] = x4.y;
        XsT[(i0 + 2) * 68 + n] = x4.z;
        XsT[(i0 + 3) * 68 + n] = x4.w;
    }
    if (t < 128) ts[t] = tvec[t];
    __syncthreads();

    const int tx = t & 15, ty = t >> 4;
    const int r0 = ty * 2;    // local row (of 32)
    const int c0 = tx * 8;    // Y col

    float acc[2][8];
    #pragma unroll
    for (int i = 0; i < 2; ++i)
        #pragma unroll
        for (int j = 0; j < 8; ++j) acc[i][j] = 0.f;

    // Y = X * G, chunked over i (4 chunks of 32)
    for (int ib = 0; ib < 4; ++ib) {
        #pragma unroll
        for (int rep = 0; rep < 4; ++rep) {
            int linear = rep * 1024 + t * 4;  // 0..4095
            int gi = linear >> 7;             // 0..31
            int gj = linear & 127;
            float4 g4 = *reinterpret_cast<const float4*>(
                G + (ib * 32 + gi) * 128 + gj);
            *reinterpret_cast<float4*>(&buf[gi * 132 + gj]) = g4;
        }
        __syncthreads();
        for (int kk = 0; kk < 32; ++kk) {
            int i = ib * 32 + kk;
            float a0 = XsT[i * 68 + half * 32 + r0];
            float a1 = XsT[i * 68 + half * 32 + r0 + 1];
            float4 b0 = *reinterpret_cast<const float4*>(&buf[kk * 132 + c0]);
            float4 b1 = *reinterpret_cast<const float4*>(&buf[kk * 132 + c0 + 4]);
            const float bv[8] = {b0.x, b0.y, b0.z, b0.w, b1.x, b1.y, b1.z, b1.w};
            #pragma unroll
            for (int j = 0; j < 8; ++j) {
                acc[0][j] += a0 * bv[j];
                acc[1][j] += a1 * bv[j];
            }
        }
        __syncthreads();
    }

    // Ys into buf
    *reinterpret_cast<float4*>(&buf[r0 * 132 + c0]) =
        make_float4(acc[0][0], acc[0][1], acc[0][2], acc[0][3]);
    *reinterpret_cast<float4*>(&buf[r0 * 132 + c0 + 4]) =
        make_float4(acc[0][4], acc[0][5], acc[0][6], acc[0][7]);
    *reinterpret_cast<float4*>(&buf[(r0 + 1) * 132 + c0]) =
        make_float4(acc[1][0], acc[1][1], acc[1][2], acc[1][3]);
    *reinterpret_cast<float4*>(&buf[(r0 + 1) * 132 + c0 + 4]) =
        make_float4(acc[1][4], acc[1][5], acc[1][6], acc[1][7]);
    __syncthreads();

    // P[n, m] = sum_j Ys[n][j] * X[m][j], thread: 2 rows x 4 cols
    const int m0 = tx * 4;
    float pacc[2][4];
    #pragma unroll
    for (int i = 0; i < 2; ++i)
        #pragma unroll
        for (int j = 0; j < 4; ++j) pacc[i][j] = 0.f;

    for (int j = 0; j < 128; ++j) {
        float a0 = buf[r0 * 132 + j];
        float a1 = buf[(r0 + 1) * 132 + j];
        float4 xm = *reinterpret_cast<const float4*>(&XsT[j * 68 + m0]);
        const float xv[4] = {xm.x, xm.y, xm.z, xm.w};
        #pragma unroll
        for (int c = 0; c < 4; ++c) {
            pacc[0][c] += a0 * xv[c];
            pacc[1][c] += a1 * xv[c];
        }
    }

    const float SCALE = 1.0f / (128.0f * 128.0f * sqrtf(128.0f));
    #pragma unroll
    for (int rr = 0; rr < 2; ++rr) {
        int ng = half * 32 + r0 + rr;
        float4 o = make_float4(pacc[rr][0] * SCALE, pacc[rr][1] * SCALE,
                               pacc[rr][2] * SCALE, pacc[rr][3] * SCALE);
        *reinterpret_cast<float4*>(P + (size_t)b * 4096 + ng * 64 + m0) = o;
    }

    // v_b (half 0 only)
    if (half == 0 && t < 64) {
        float s = 0.f;
        for (int i = 0; i < 128; ++i) s += XsT[i * 68 + t] * ts[i];
        V[b * 64 + t] = s;
    }
}

// ---------------------------------------------------------------------------
// Kernel 4: per-batch softmax stats (max, sum) via flash-combine partials
// Block (s, b): 256 threads, one (n,m) pair per thread.
// ---------------------------------------------------------------------------
__global__ __launch_bounds__(256) void k_stats(const float* __restrict__ P,
                                               const float* __restrict__ V,
                                               const float* __restrict__ seq,
                                               float* __restrict__ spart) {
    __shared__ float vl[64];
    __shared__ int   fl[64];
    __shared__ float rm[256], rs[256];
    const int s = blockIdx.x;   // 0..15
    const int b = blockIdx.y;   // 0..127
    const int t = threadIdx.x;

    if (t < 64) {
        vl[t] = V[b * 64 + t];
        fl[t] = (seq[t * NB + b] > 0.f) ? 1 : 0;
    }
    __syncthreads();

    const int pair = s * 256 + t;
    const int n = pair >> 6, m = pair & 63;
    const int ok_nm = fl[n] && fl[m] && (n != m);
    const float a = P[(size_t)b * 4096 + pair];

    float mx = -INFINITY;
    #pragma unroll
    for (int l = 0; l < 64; ++l) {
        bool ok = ok_nm && fl[l] && (l != n) && (l != m);
        float z = a * vl[l];
        mx = ok ? fmaxf(mx, z) : mx;
    }
    float sm = 0.f;
    if (ok_nm) {
        #pragma unroll
        for (int l = 0; l < 64; ++l) {
            bool ok = fl[l] && (l != n) && (l != m);
            float e = __expf(a * vl[l] - mx);
            sm += ok ? e : 0.f;
        }
    }
    rm[t] = mx; rs[t] = sm;
    __syncthreads();

    for (int stp = 128; stp > 0; stp >>= 1) {
        if (t < stp) {
            float m1 = rm[t], m2 = rm[t + stp];
            float mm = fmaxf(m1, m2);
            float ss = 0.f;
            if (mm != -INFINITY)
                ss = rs[t] * __expf(m1 - mm) + rs[t + stp] * __expf(m2 - mm);
            rm[t] = mm; rs[t] = ss;
        }
        __syncthreads();
    }
    if (t == 0) {
        spart[(b * 16 + s) * 2]     = rm[0];
        spart[(b * 16 + s) * 2 + 1] = rs[0];
    }
}

// ---------------------------------------------------------------------------
// Kernel 5: combine 16 partials per batch -> (max, 1/denom)
// ---------------------------------------------------------------------------
__global__ __launch_bounds__(64) void k_comb(const float* __restrict__ spart,
                                             float* __restrict__ stat) {
    const int b = blockIdx.x;
    if (threadIdx.x == 0) {
        float mm = -INFINITY, ss = 0.f;
        for (int i = 0; i < 16; ++i) {
            float m2 = spart[(b * 16 + i) * 2];
            float s2 = spart[(b * 16 + i) * 2 + 1];
            float mn = fmaxf(mm, m2);
            if (mn != -INFINITY) {
                ss = ss * __expf(mm - mn) + s2 * __expf(m2 - mn);
                mm = mn;
            }
        }
        stat[b * 2]     = mm;
        stat[b * 2 + 1] = 1.0f / ss;
    }
}

// ---------------------------------------------------------------------------
// Kernel 6: write output: out[b,n,m,l] = mask * exp(P*v - max) * invden
// Block (n, b): 64x64 slab, thread -> (m = t>>2, 16 contiguous l)
// ---------------------------------------------------------------------------
__global__ __launch_bounds__(256) void k_out(const float* __restrict__ P,
                                             const float* __restrict__ V,
                                             const float* __restrict__ seq,
                                             const float* __restrict__ stat,
                                             float* __restrict__ out) {
    __shared__ float vl[64];
    __shared__ int   fl[64];
    __shared__ float prow[64];
    __shared__ float smx, sinv;
    const int n = blockIdx.x;   // 0..63
    const int b = blockIdx.y;   // 0..127
    const int t = threadIdx.x;

    if (t < 64) {
        vl[t]   = V[b * 64 + t];
        fl[t]   = (seq[t * NB + b] > 0.f) ? 1 : 0;
        prow[t] = P[(size_t)b * 4096 + n * 64 + t];
    }
    if (t == 64) smx  = stat[b * 2];
    if (t == 65) sinv = stat[b * 2 + 1];
    __syncthreads();

    const int m  = t >> 2;
    const int l0 = (t & 3) << 4;
    const float a   = prow[m];
    const int okm   = fl[n] && fl[m] && (m != n);
    const float mx  = smx;
    const float inv = sinv;

    float* dst = out + ((size_t)b << 18) + ((size_t)n << 12) + (m << 6) + l0;
    #pragma unroll
    for (int c = 0; c < 4; ++c) {
        float o[4];
        #pragma unroll
        for (int j = 0; j < 4; ++j) {
            int l = l0 + c * 4 + j;
            bool ok = okm && fl[l] && (l != n) && (l != m);
            o[j] = ok ? __expf(a * vl[l] - mx) * inv : 0.f;
        }
        *reinterpret_cast<float4*>(dst + c * 4) = make_float4(o[0], o[1], o[2], o[3]);
    }
}

// ---------------------------------------------------------------------------
extern "C" void kernel_launch(void* const* d_in, const int* in_sizes, int n_in,
                              void* d_out, int out_size, void* d_ws, size_t ws_size,
                              hipStream_t stream) {
    const float* x   = (const float*)d_in[0];
    const float* seq = (const float*)d_in[1];
    const float* W   = (const float*)d_in[2];
    float* ws    = (float*)d_ws;
    float* gpart = ws + WS_GPART;
    float* G     = ws + WS_G;
    float* tvec  = ws + WS_T;
    float* P     = ws + WS_P;
    float* V     = ws + WS_V;
    float* spart = ws + WS_SPART;
    float* stat  = ws + WS_STAT;
    float* out   = (float*)d_out;

    k_gpart  <<<dim3(128, 2), 256, 0, stream>>>(W, gpart);
    k_greduce<<<64, 256, 0, stream>>>(gpart, W, G, tvec);
    k_pv     <<<dim3(128, 2), 256, 0, stream>>>(x, G, tvec, P, V);
    k_stats  <<<dim3(16, 128), 256, 0, stream>>>(P, V, seq, spart);
    k_comb   <<<128, 64, 0, stream>>>(spart, stat);
    k_out    <<<dim3(64, 128), 256, 0, stream>>>(P, V, seq, stat, out);
}

// Round 2
// 96.268 us; speedup vs baseline: 1.3086x; 1.3086x over previous
//
#include <hip/hip_runtime.h>
#include <math.h>

#define NB 128     // BATCH

// workspace layout (float offsets)
#define WS_GPART 0                            // 256 chunks * 16384
#define WS_G     (256 * 16384)                // 16384
#define WS_T     (WS_G + 16384)               // 128
#define WS_P     (WS_T + 128)                 // 128*64*64 (scaled P)
#define WS_V     (WS_P + 524288)              // 128*64
#define WS_S     (WS_V + 8192)                // 128 (1/denom)

// ---------------------------------------------------------------------------
// Kernel 1: partial gram  gpart[c] = A_c * A_c^T, A = W viewed (128, 16384),
// chunk c = 64 K-columns. 256 blocks x 512 threads (2 waves/SIMD).
// ---------------------------------------------------------------------------
__global__ __launch_bounds__(512) void k_gpart(const float* __restrict__ W,
                                               float* __restrict__ gpart) {
    __shared__ float As[64 * 132];    // [k][n], n padded to 132
    const int c = blockIdx.x;         // 0..255
    const int t = threadIdx.x;        // 0..511

    // load tile transposed: As[k][n] = W[n*16384 + c*64 + k]
    #pragma unroll
    for (int rep = 0; rep < 4; ++rep) {
        int linear = rep * 2048 + t * 4;      // 0..8191
        int n  = linear >> 6;                 // 0..127
        int k0 = linear & 63;
        float4 w4 = *reinterpret_cast<const float4*>(
            W + (size_t)n * 16384 + c * 64 + k0);
        As[(k0 + 0) * 132 + n] = w4.x;
        As[(k0 + 1) * 132 + n] = w4.y;
        As[(k0 + 2) * 132 + n] = w4.z;
        As[(k0 + 3) * 132 + n] = w4.w;
    }
    __syncthreads();

    const int tx = t & 15, ty = t >> 4;   // tx 0..15, ty 0..31
    const int row0 = ty * 4;              // 4 rows
    const int col0 = tx * 8;              // 8 cols
    float acc[4][8];
    #pragma unroll
    for (int i = 0; i < 4; ++i)
        #pragma unroll
        for (int j = 0; j < 8; ++j) acc[i][j] = 0.f;

    for (int k = 0; k < 64; ++k) {
        float4 a  = *reinterpret_cast<const float4*>(&As[k * 132 + row0]);
        float4 b0 = *reinterpret_cast<const float4*>(&As[k * 132 + col0]);
        float4 b1 = *reinterpret_cast<const float4*>(&As[k * 132 + col0 + 4]);
        const float av[4] = {a.x, a.y, a.z, a.w};
        const float bv[8] = {b0.x, b0.y, b0.z, b0.w, b1.x, b1.y, b1.z, b1.w};
        #pragma unroll
        for (int i = 0; i < 4; ++i)
            #pragma unroll
            for (int j = 0; j < 8; ++j) acc[i][j] += av[i] * bv[j];
    }

    float* gp = gpart + (size_t)c * 16384;
    #pragma unroll
    for (int i = 0; i < 4; ++i) {
        *reinterpret_cast<float4*>(gp + (row0 + i) * 128 + col0) =
            make_float4(acc[i][0], acc[i][1], acc[i][2], acc[i][3]);
        *reinterpret_cast<float4*>(gp + (row0 + i) * 128 + col0 + 4) =
            make_float4(acc[i][4], acc[i][5], acc[i][6], acc[i][7]);
    }
}

// ---------------------------------------------------------------------------
// Kernel 2: blocks 0..255 reduce 256 partials -> G; blocks 256..383 do trace.
// ---------------------------------------------------------------------------
__global__ __launch_bounds__(256) void k_greduce(const float* __restrict__ gpart,
                                                 const float* __restrict__ W,
                                                 float* __restrict__ G,
                                                 float* __restrict__ tvec) {
    __shared__ float red[256];
    __shared__ float w2[4];
    const int blk = blockIdx.x;
    const int t = threadIdx.x;

    if (blk < 256) {
        const int oo = t & 63, cg = t >> 6;     // 64 outputs x 4 chunk-groups
        const int o = blk * 64 + oo;
        float s = 0.f;
        for (int j = 0; j < 64; ++j)
            s += gpart[(size_t)(cg * 64 + j) * 16384 + o];
        red[cg * 64 + oo] = s;
        __syncthreads();
        if (t < 64)
            G[blk * 64 + t] = red[t] + red[64 + t] + red[128 + t] + red[192 + t];
    } else {
        const int i = blk - 256;                // 0..127
        float s = (t < 128) ? W[(size_t)i * 16384 + t * 129] : 0.f;
        #pragma unroll
        for (int off = 32; off > 0; off >>= 1) s += __shfl_down(s, off, 64);
        if ((t & 63) == 0) w2[t >> 6] = s;
        __syncthreads();
        if (t == 0) tvec[i] = w2[0] + w2[1];
    }
}

// ---------------------------------------------------------------------------
// Kernel 3: per (b, half): 32 rows of Y = X_b G, P = (Y X_b^T)*scale, v = X_b t
// 512 threads, ~53 KiB LDS (3 blocks/CU).
// ---------------------------------------------------------------------------
__global__ __launch_bounds__(512) void k_pv(const float* __restrict__ x,
                                            const float* __restrict__ G,
                                            const float* __restrict__ tvec,
                                            float* __restrict__ P,
                                            float* __restrict__ V) {
    __shared__ float XsT[128 * 68];   // [i][n], n<64 padded to 68
    __shared__ float buf[32 * 132];   // G chunk, then Ys
    __shared__ float ts[128];
    __shared__ float vred[128];
    const int b    = blockIdx.x;      // 0..127
    const int half = blockIdx.y;      // 0..1
    const int t = threadIdx.x;        // 0..511

    // XsT[i][n] = x[n*16384 + b*128 + i]
    #pragma unroll
    for (int rep = 0; rep < 4; ++rep) {
        int linear = rep * 2048 + t * 4;   // 0..8191
        int n  = linear >> 7;              // 0..63
        int i0 = linear & 127;
        float4 x4 = *reinterpret_cast<const float4*>(
            x + (size_t)n * 16384 + b * 128 + i0);
        XsT[(i0 + 0) * 68 + n] = x4.x;
        XsT[(i0 + 1) * 68 + n] = x4.y;
        XsT[(i0 + 2) * 68 + n] = x4.z;
        XsT[(i0 + 3) * 68 + n] = x4.w;
    }
    if (t < 128) ts[t] = tvec[t];
    __syncthreads();

    const int tx = t & 15, ty = t >> 4;   // tx 0..15, ty 0..31
    const int r  = ty;                    // local Y row
    const int c0 = tx * 8;                // Y col
    float acc[8];
    #pragma unroll
    for (int j = 0; j < 8; ++j) acc[j] = 0.f;

    for (int ib = 0; ib < 4; ++ib) {
        #pragma unroll
        for (int rep = 0; rep < 2; ++rep) {
            int linear = rep * 2048 + t * 4;  // 0..4095
            int gi = linear >> 7;             // 0..31
            int gj = linear & 127;
            *reinterpret_cast<float4*>(&buf[gi * 132 + gj]) =
                *reinterpret_cast<const float4*>(&G[(ib * 32 + gi) * 128 + gj]);
        }
        __syncthreads();
        for (int kk = 0; kk < 32; ++kk) {
            int i = ib * 32 + kk;
            float a0 = XsT[i * 68 + half * 32 + r];
            float4 b0 = *reinterpret_cast<const float4*>(&buf[kk * 132 + c0]);
            float4 b1 = *reinterpret_cast<const float4*>(&buf[kk * 132 + c0 + 4]);
            acc[0] += a0 * b0.x; acc[1] += a0 * b0.y;
            acc[2] += a0 * b0.z; acc[3] += a0 * b0.w;
            acc[4] += a0 * b1.x; acc[5] += a0 * b1.y;
            acc[6] += a0 * b1.z; acc[7] += a0 * b1.w;
        }
        __syncthreads();
    }

    // Ys into buf
    *reinterpret_cast<float4*>(&buf[r * 132 + c0]) =
        make_float4(acc[0], acc[1], acc[2], acc[3]);
    *reinterpret_cast<float4*>(&buf[r * 132 + c0 + 4]) =
        make_float4(acc[4], acc[5], acc[6], acc[7]);
    __syncthreads();

    // P[n][m] = sum_j Ys[r][j] * X[m][j]; thread: 1 row x 4 cols
    const int m0 = tx * 4;
    float pacc[4] = {0.f, 0.f, 0.f, 0.f};
    for (int j = 0; j < 128; ++j) {
        float a0 = buf[r * 132 + j];
        float4 xm = *reinterpret_cast<const float4*>(&XsT[j * 68 + m0]);
        pacc[0] += a0 * xm.x; pacc[1] += a0 * xm.y;
        pacc[2] += a0 * xm.z; pacc[3] += a0 * xm.w;
    }
    const float SCALE = 1.0f / (128.0f * 128.0f * sqrtf(128.0f));
    *reinterpret_cast<float4*>(P + (size_t)b * 4096 + (half * 32 + r) * 64 + m0) =
        make_float4(pacc[0] * SCALE, pacc[1] * SCALE,
                    pacc[2] * SCALE, pacc[3] * SCALE);

    // v_b (half 0 only): v[l] = sum_i X[l][i] t[i]
    if (half == 0) {
        if (t < 128) {
            const int l = t & 63, g = t >> 6;
            float s = 0.f;
            for (int i = g * 64; i < g * 64 + 64; ++i)
                s += XsT[i * 68 + l] * ts[i];
            vred[t] = s;
        }
        __syncthreads();
        if (t < 64) V[b * 64 + t] = vred[t] + vred[64 + t];
    }
}

// ---------------------------------------------------------------------------
// Kernel 4: denominator per batch (no max subtraction; |z| < ~1 is safe).
// 128 blocks x 1024 threads; thread handles 4 consecutive (n,m) pairs.
// ---------------------------------------------------------------------------
__global__ __launch_bounds__(1024) void k_den(const float* __restrict__ P,
                                              const float* __restrict__ V,
                                              const float* __restrict__ seq,
                                              float* __restrict__ stat) {
    __shared__ float vl[64];
    __shared__ int   fl[64];
    __shared__ float part[16];
    const int b = blockIdx.x;
    const int t = threadIdx.x;

    if (t < 64) {
        vl[t] = V[b * 64 + t];
        fl[t] = (seq[t * NB + b] > 0.f) ? 1 : 0;
    }
    __syncthreads();

    float4 a4 = *reinterpret_cast<const float4*>(P + (size_t)b * 4096 + t * 4);
    const float aj[4] = {a4.x, a4.y, a4.z, a4.w};
    int nj[4], mj[4], okj[4];
    #pragma unroll
    for (int j = 0; j < 4; ++j) {
        int p = t * 4 + j;
        nj[j] = p >> 6; mj[j] = p & 63;
        okj[j] = fl[nj[j]] && fl[mj[j]] && (nj[j] != mj[j]);
    }

    float s = 0.f;
    for (int l = 0; l < 64; ++l) {
        if (!fl[l]) continue;          // wave-uniform branch
        float vv = vl[l];
        #pragma unroll
        for (int j = 0; j < 4; ++j)
            s += okj[j] ? __expf(aj[j] * vv) : 0.f;
    }
    // remove l==n and l==m terms (both valid when okj)
    #pragma unroll
    for (int j = 0; j < 4; ++j)
        if (okj[j])
            s -= __expf(aj[j] * vl[nj[j]]) + __expf(aj[j] * vl[mj[j]]);

    #pragma unroll
    for (int off = 32; off > 0; off >>= 1) s += __shfl_down(s, off, 64);
    if ((t & 63) == 0) part[t >> 6] = s;
    __syncthreads();
    if (t == 0) {
        float tot = 0.f;
        #pragma unroll
        for (int w = 0; w < 16; ++w) tot += part[w];
        stat[b] = 1.0f / tot;
    }
}

// ---------------------------------------------------------------------------
// Kernel 5: out[b,n,m,l] = mask * exp(P[n,m]*v[l]) * invden
// ---------------------------------------------------------------------------
__global__ __launch_bounds__(256) void k_out(const float* __restrict__ P,
                                             const float* __restrict__ V,
                                             const float* __restrict__ seq,
                                             const float* __restrict__ stat,
                                             float* __restrict__ out) {
    __shared__ float vl[64];
    __shared__ int   fl[64];
    __shared__ float prow[64];
    __shared__ float sinv;
    const int n = blockIdx.x;   // 0..63
    const int b = blockIdx.y;   // 0..127
    const int t = threadIdx.x;

    if (t < 64) {
        vl[t]   = V[b * 64 + t];
        fl[t]   = (seq[t * NB + b] > 0.f) ? 1 : 0;
        prow[t] = P[(size_t)b * 4096 + n * 64 + t];
    }
    if (t == 64) sinv = stat[b];
    __syncthreads();

    const int m  = t >> 2;
    const int l0 = (t & 3) << 4;
    const float a   = prow[m];
    const int   okm = fl[n] && fl[m] && (m != n);
    const float inv = sinv;

    float* dst = out + ((size_t)b << 18) + (n << 12) + (m << 6) + l0;
    #pragma unroll
    for (int c = 0; c < 4; ++c) {
        float o[4];
        #pragma unroll
        for (int j = 0; j < 4; ++j) {
            int l = l0 + c * 4 + j;
            bool ok = okm && fl[l] && (l != n) && (l != m);
            o[j] = ok ? __expf(a * vl[l]) * inv : 0.f;
        }
        *reinterpret_cast<float4*>(dst + c * 4) = make_float4(o[0], o[1], o[2], o[3]);
    }
}

// ---------------------------------------------------------------------------
extern "C" void kernel_launch(void* const* d_in, const int* in_sizes, int n_in,
                              void* d_out, int out_size, void* d_ws, size_t ws_size,
                              hipStream_t stream) {
    const float* x   = (const float*)d_in[0];
    const float* seq = (const float*)d_in[1];
    const float* W   = (const float*)d_in[2];
    float* ws    = (float*)d_ws;
    float* gpart = ws + WS_GPART;
    float* G     = ws + WS_G;
    float* tvec  = ws + WS_T;
    float* P     = ws + WS_P;
    float* V     = ws + WS_V;
    float* stat  = ws + WS_S;
    float* out   = (float*)d_out;

    k_gpart  <<<256, 512, 0, stream>>>(W, gpart);
    k_greduce<<<384, 256, 0, stream>>>(gpart, W, G, tvec);
    k_pv     <<<dim3(128, 2), 512, 0, stream>>>(x, G, tvec, P, V);
    k_den    <<<128, 1024, 0, stream>>>(P, V, seq, stat);
    k_out    <<<dim3(64, 128), 256, 0, stream>>>(P, V, seq, stat, out);
}

// Round 4
// 82.674 us; speedup vs baseline: 1.5238x; 1.1644x over previous
//
#include <hip/hip_runtime.h>
#include <math.h>

#define NB 128     // BATCH

typedef short s16x8 __attribute__((ext_vector_type(8)));
typedef float f32x16 __attribute__((ext_vector_type(16)));
typedef float f32x4 __attribute__((ext_vector_type(4)));

// workspace layout (byte offsets, all 16B aligned)
#define WSB_GPART 0u                       // 128 * 16384 fp32 = 8 MB
#define WSB_GH    8388608u                 // 16384 bf16 = 32 KB
#define WSB_T     8421376u                 // 128 fp32
#define WSB_P     8421888u                 // 128*64*64 fp32 = 2 MB
#define WSB_V     10519040u                // 128*64 fp32 = 32 KB
#define WSB_S     10551808u                // 128 fp32

static __device__ __forceinline__ unsigned short f2bf(float f) {
    unsigned int u = __float_as_uint(f);
    return (unsigned short)((u + 0x7fffu + ((u >> 16) & 1u)) >> 16);
}
static __device__ __forceinline__ float bf2f(unsigned short h) {
    return __uint_as_float(((unsigned int)h) << 16);
}

// ---------------------------------------------------------------------------
// Kernel 1: gram partials via MFMA.  G = Wf * Wf^T, Wf = W viewed (128,16384).
// Block (kc, rh): K-chunk of 128, output rows rh*64..+63. Stages the full
// 128x128 W chunk fp32->bf16 into a swizzled LDS tile; 8 waves x 1 tile each.
// ---------------------------------------------------------------------------
__global__ __launch_bounds__(512) void k_gram(const float* __restrict__ W,
                                              float* __restrict__ gpart) {
    __shared__ char WS[32768];   // [128 rows][128 k] bf16, XOR-swizzled
    const int kc = blockIdx.x;   // 0..127
    const int rh = blockIdx.y;   // 0..1
    const int t = threadIdx.x;

    // stage: 4096 float4 chunks, 8 per thread, convert to bf16
    #pragma unroll
    for (int rep = 0; rep < 8; ++rep) {
        int ch = rep * 512 + t;
        int row = ch >> 5, f4 = ch & 31;
        float4 w4 = *reinterpret_cast<const float4*>(
            W + (size_t)row * 16384 + kc * 128 + f4 * 4);
        ushort4 h = make_ushort4(f2bf(w4.x), f2bf(w4.y), f2bf(w4.z), f2bf(w4.w));
        *reinterpret_cast<ushort4*>(WS + row * 256 + ((f4 * 8) ^ ((row & 7) << 4))) = h;
    }
    __syncthreads();

    const int wid = t >> 6, l = t & 63;
    const int lr = l & 31, lhi = l >> 5;
    const int r = rh * 2 + (wid >> 2);   // output row-tile 0..3
    const int c = wid & 3;               // output col-tile 0..3

    f32x16 acc;
    #pragma unroll
    for (int i = 0; i < 16; ++i) acc[i] = 0.f;

    const int arow = r * 32 + lr;
    const int brow = c * 32 + lr;
    #pragma unroll
    for (int kk = 0; kk < 8; ++kk) {
        int kb = kk * 32 + lhi * 16;
        s16x8 a = *reinterpret_cast<const s16x8*>(WS + arow * 256 + (kb ^ ((arow & 7) << 4)));
        s16x8 bb = *reinterpret_cast<const s16x8*>(WS + brow * 256 + (kb ^ ((brow & 7) << 4)));
        acc = __builtin_amdgcn_mfma_f32_32x32x16_bf16(a, bb, acc, 0, 0, 0);
    }

    float* gp = gpart + (size_t)kc * 16384;
    #pragma unroll
    for (int reg = 0; reg < 16; ++reg) {
        int row = r * 32 + (reg & 3) + 8 * (reg >> 2) + 4 * lhi;
        __builtin_nontemporal_store(acc[reg], gp + row * 128 + c * 32 + lr);
    }
}

// ---------------------------------------------------------------------------
// Kernel 2: blocks 0..127 reduce partials -> Gh (bf16); blocks 128..129 trace.
// ---------------------------------------------------------------------------
__global__ __launch_bounds__(256) void k_gred(const float* __restrict__ gpart,
                                              const float* __restrict__ W,
                                              unsigned short* __restrict__ Gh,
                                              float* __restrict__ tvec) {
    __shared__ float red[256];
    const int blk = blockIdx.x;
    const int t = threadIdx.x;

    if (blk < 128) {
        const int oo = t & 127, cg = t >> 7;
        const size_t o = (size_t)blk * 128 + oo;
        float s = 0.f;
        for (int ch = cg * 64; ch < cg * 64 + 64; ++ch)
            s += gpart[(size_t)ch * 16384 + o];
        red[t] = s;
        __syncthreads();
        if (t < 128) Gh[o] = f2bf(red[t] + red[t + 128]);
    } else {
        const int iloc = t >> 2, q = t & 3;
        const int i = (blk - 128) * 64 + iloc;
        float s = 0.f;
        for (int a = q * 32; a < q * 32 + 32; ++a)
            s += W[(size_t)i * 16384 + a * 129];
        red[t] = s;
        __syncthreads();
        if (q == 0)
            tvec[i] = red[iloc * 4] + red[iloc * 4 + 1] +
                      red[iloc * 4 + 2] + red[iloc * 4 + 3];
    }
}

// ---------------------------------------------------------------------------
// Kernel 3: per (b, half): Y = Xb G (MFMA), P = (Y Xb^T)*scale (MFMA), v = Xb t
// Stages x fp32->bf16 and Gh into swizzled LDS. 4 waves.
// ---------------------------------------------------------------------------
__global__ __launch_bounds__(256) void k_pv(const float* __restrict__ x,
                                            const unsigned short* __restrict__ Gh,
                                            const float* __restrict__ tvec,
                                            float* __restrict__ P,
                                            float* __restrict__ V) {
    __shared__ char XS[16384];   // [64 jets][128] bf16 swz
    __shared__ char GS[32768];   // [128][128] bf16 swz (G symmetric)
    __shared__ char YS[8192];    // [32 rows][128] bf16 swz
    __shared__ float ts[128];
    const int b    = blockIdx.x;
    const int half = blockIdx.y;
    const int t = threadIdx.x;

    // stage Xb: 2048 float4, 8/thread; XS[j][i] = x[j][b][i]
    #pragma unroll
    for (int rep = 0; rep < 8; ++rep) {
        int ch = rep * 256 + t;
        int row = ch >> 5, f4 = ch & 31;
        float4 x4 = *reinterpret_cast<const float4*>(
            x + (size_t)row * 16384 + b * 128 + f4 * 4);
        ushort4 h = make_ushort4(f2bf(x4.x), f2bf(x4.y), f2bf(x4.z), f2bf(x4.w));
        *reinterpret_cast<ushort4*>(XS + row * 256 + ((f4 * 8) ^ ((row & 7) << 4))) = h;
    }
    // stage Gh: 2048 16B chunks, 8/thread
    #pragma unroll
    for (int rep = 0; rep < 8; ++rep) {
        int ch = rep * 256 + t;
        int row = ch >> 4, kb = ch & 15;
        uint4 g4 = *reinterpret_cast<const uint4*>(Gh + row * 128 + kb * 8);
        *reinterpret_cast<uint4*>(GS + row * 256 + ((kb * 16) ^ ((row & 7) << 4))) = g4;
    }
    if (t < 128) ts[t] = tvec[t];
    __syncthreads();

    const int wid = t >> 6, l = t & 63, lr = l & 31, lhi = l >> 5;

    // Y-stage: wave wid -> Y col-tile wid (rows = half*32..+31)
    f32x16 acc;
    #pragma unroll
    for (int i = 0; i < 16; ++i) acc[i] = 0.f;
    {
        const int arow = half * 32 + lr;   // jet row
        const int brow = wid * 32 + lr;    // G row (== col, symmetric)
        #pragma unroll
        for (int kk = 0; kk < 8; ++kk) {
            int kb = kk * 32 + lhi * 16;
            s16x8 a = *reinterpret_cast<const s16x8*>(XS + arow * 256 + (kb ^ ((arow & 7) << 4)));
            s16x8 g = *reinterpret_cast<const s16x8*>(GS + brow * 256 + (kb ^ ((brow & 7) << 4)));
            acc = __builtin_amdgcn_mfma_f32_32x32x16_bf16(a, g, acc, 0, 0, 0);
        }
    }
    // Y (fp32 acc) -> YS bf16, local rows 0..31
    #pragma unroll
    for (int reg = 0; reg < 16; ++reg) {
        int row = (reg & 3) + 8 * (reg >> 2) + 4 * lhi;
        int col = wid * 32 + lr;
        *reinterpret_cast<unsigned short*>(
            YS + row * 256 + ((2 * col) ^ ((row & 7) << 4))) = f2bf(acc[reg]);
    }
    __syncthreads();

    if (wid < 2) {
        // P-stage: tile cols m = wid*32..+31, K = 128 (Y cols)
        f32x16 pa;
        #pragma unroll
        for (int i = 0; i < 16; ++i) pa[i] = 0.f;
        const int arow = lr;             // Y local row
        const int brow = wid * 32 + lr;  // jet m
        #pragma unroll
        for (int kk = 0; kk < 8; ++kk) {
            int kb = kk * 32 + lhi * 16;
            s16x8 a = *reinterpret_cast<const s16x8*>(YS + arow * 256 + (kb ^ ((arow & 7) << 4)));
            s16x8 bb = *reinterpret_cast<const s16x8*>(XS + brow * 256 + (kb ^ ((brow & 7) << 4)));
            pa = __builtin_amdgcn_mfma_f32_32x32x16_bf16(a, bb, pa, 0, 0, 0);
        }
        const float SCALE = 1.0f / (128.0f * 128.0f * sqrtf(128.0f));
        #pragma unroll
        for (int reg = 0; reg < 16; ++reg) {
            int n = half * 32 + (reg & 3) + 8 * (reg >> 2) + 4 * lhi;
            int m = wid * 32 + lr;
            P[(size_t)b * 4096 + n * 64 + m] = pa[reg] * SCALE;
        }
    } else if (wid == 2 && half == 0) {
        // v[l] = sum_i Xb[l][i] * t[i]
        float s = 0.f;
        #pragma unroll
        for (int kb = 0; kb < 16; ++kb) {
            uint4 c4 = *reinterpret_cast<const uint4*>(
                XS + l * 256 + ((kb * 16) ^ ((l & 7) << 4)));
            const unsigned short* hp = reinterpret_cast<const unsigned short*>(&c4);
            #pragma unroll
            for (int e = 0; e < 8; ++e)
                s += bf2f(hp[e]) * ts[kb * 8 + e];
        }
        V[b * 64 + l] = s;
    }
}

// ---------------------------------------------------------------------------
// Kernel 4: denominator per batch (no max subtraction; |z| <= ~0.1).
// ---------------------------------------------------------------------------
__global__ __launch_bounds__(1024) void k_den(const float* __restrict__ P,
                                              const float* __restrict__ V,
                                              const float* __restrict__ seq,
                                              float* __restrict__ stat) {
    __shared__ float vl[64];
    __shared__ int   fl[64];
    __shared__ float part[16];
    const int b = blockIdx.x;
    const int t = threadIdx.x;

    if (t < 64) {
        vl[t] = V[b * 64 + t];
        fl[t] = (seq[t * NB + b] > 0.f) ? 1 : 0;
    }
    __syncthreads();

    float4 a4 = *reinterpret_cast<const float4*>(P + (size_t)b * 4096 + t * 4);
    const float aj[4] = {a4.x, a4.y, a4.z, a4.w};
    int nj[4], mj[4], okj[4];
    #pragma unroll
    for (int j = 0; j < 4; ++j) {
        int p = t * 4 + j;
        nj[j] = p >> 6; mj[j] = p & 63;
        okj[j] = fl[nj[j]] && fl[mj[j]] && (nj[j] != mj[j]);
    }

    float s = 0.f;
    for (int l = 0; l < 64; ++l) {
        if (!fl[l]) continue;
        float vv = vl[l];
        #pragma unroll
        for (int j = 0; j < 4; ++j)
            s += okj[j] ? __expf(aj[j] * vv) : 0.f;
    }
    #pragma unroll
    for (int j = 0; j < 4; ++j)
        if (okj[j])
            s -= __expf(aj[j] * vl[nj[j]]) + __expf(aj[j] * vl[mj[j]]);

    #pragma unroll
    for (int off = 32; off > 0; off >>= 1) s += __shfl_down(s, off, 64);
    if ((t & 63) == 0) part[t >> 6] = s;
    __syncthreads();
    if (t == 0) {
        float tot = 0.f;
        #pragma unroll
        for (int w = 0; w < 16; ++w) tot += part[w];
        stat[b] = 1.0f / tot;
    }
}

// ---------------------------------------------------------------------------
// Kernel 5: out[b,n,m,l] = mask * exp(P[n,m]*v[l]) * invden
// Wave stores are 1KB-contiguous; nontemporal (134 MB stream).
// ---------------------------------------------------------------------------
__global__ __launch_bounds__(256) void k_out(const float* __restrict__ P,
                                             const float* __restrict__ V,
                                             const float* __restrict__ seq,
                                             const float* __restrict__ stat,
                                             float* __restrict__ out) {
    __shared__ float vl[64];
    __shared__ int   fl[64];
    __shared__ float prow[64];
    __shared__ float sinv_s;
    const int n = blockIdx.x;   // 0..63
    const int b = blockIdx.y;   // 0..127
    const int t = threadIdx.x;

    if (t < 64) {
        vl[t]   = V[b * 64 + t];
        fl[t]   = (seq[t * NB + b] > 0.f) ? 1 : 0;
        prow[t] = P[(size_t)b * 4096 + n * 64 + t];
    }
    if (t == 64) sinv_s = stat[b];
    __syncthreads();

    const int fln = fl[n];
    const float inv = sinv_s;
    float* slab = out + ((size_t)b << 18) + (n << 12);
    #pragma unroll
    for (int c = 0; c < 4; ++c) {
        int idx = c * 1024 + t * 4;
        int m = idx >> 6;
        int l0 = idx & 63;
        float a = prow[m];
        bool okm = fln && fl[m] && (m != n);
        f32x4 o;
        {
            int l = l0;
            o[0] = (okm && fl[l] && (l != n) && (l != m)) ? __expf(a * vl[l]) * inv : 0.f;
            l = l0 + 1;
            o[1] = (okm && fl[l] && (l != n) && (l != m)) ? __expf(a * vl[l]) * inv : 0.f;
            l = l0 + 2;
            o[2] = (okm && fl[l] && (l != n) && (l != m)) ? __expf(a * vl[l]) * inv : 0.f;
            l = l0 + 3;
            o[3] = (okm && fl[l] && (l != n) && (l != m)) ? __expf(a * vl[l]) * inv : 0.f;
        }
        __builtin_nontemporal_store(o, reinterpret_cast<f32x4*>(slab + idx));
    }
}

// ---------------------------------------------------------------------------
extern "C" void kernel_launch(void* const* d_in, const int* in_sizes, int n_in,
                              void* d_out, int out_size, void* d_ws, size_t ws_size,
                              hipStream_t stream) {
    const float* x   = (const float*)d_in[0];
    const float* seq = (const float*)d_in[1];
    const float* W   = (const float*)d_in[2];
    char* wsb = (char*)d_ws;
    float*          gpart = (float*)(wsb + WSB_GPART);
    unsigned short* Gh    = (unsigned short*)(wsb + WSB_GH);
    float*          tvec  = (float*)(wsb + WSB_T);
    float*          P     = (float*)(wsb + WSB_P);
    float*          V     = (float*)(wsb + WSB_V);
    float*          stat  = (float*)(wsb + WSB_S);
    float* out = (float*)d_out;

    k_gram<<<dim3(128, 2), 512, 0, stream>>>(W, gpart);
    k_gred<<<130, 256, 0, stream>>>(gpart, W, Gh, tvec);
    k_pv  <<<dim3(128, 2), 256, 0, stream>>>(x, Gh, tvec, P, V);
    k_den <<<128, 1024, 0, stream>>>(P, V, seq, stat);
    k_out <<<dim3(64, 128), 256, 0, stream>>>(P, V, seq, stat, out);
}

// Round 5
// 82.005 us; speedup vs baseline: 1.5363x; 1.0082x over previous
//
#include <hip/hip_runtime.h>
#include <math.h>

#define NB 128     // BATCH

typedef short s16x8 __attribute__((ext_vector_type(8)));
typedef float f32x16 __attribute__((ext_vector_type(16)));
typedef float f32x4 __attribute__((ext_vector_type(4)));

// workspace layout (byte offsets, all >=512B aligned)
#define WSB_GPART 0u                       // 128 chunks * 16384 bf16 = 4 MB
#define WSB_GH    4194304u                 // 16384 bf16 = 32 KB
#define WSB_T     4227072u                 // 128 fp32
#define WSB_P     4227584u                 // 128*64*64 fp32 = 2 MB
#define WSB_V     6324736u                 // 128*64 fp32 = 32 KB
#define WSB_S     6357504u                 // 128 fp32

static __device__ __forceinline__ unsigned short f2bf(float f) {
    unsigned int u = __float_as_uint(f);
    return (unsigned short)((u + 0x7fffu + ((u >> 16) & 1u)) >> 16);
}
static __device__ __forceinline__ float bf2f(unsigned short h) {
    return __uint_as_float(((unsigned int)h) << 16);
}

// ---------------------------------------------------------------------------
// Kernel 1: gram partials via MFMA.  G = Wf * Wf^T, Wf = W viewed (128,16384).
// Block kc: K-chunk of 128. 16 waves -> all 16 output 32x32 tiles; W read ONCE.
// Partials stored bf16 (4 MB round-trip instead of 8).
// ---------------------------------------------------------------------------
__global__ __launch_bounds__(1024) void k_gram(const float* __restrict__ W,
                                               unsigned short* __restrict__ gpart) {
    __shared__ char WS[32768];   // [128 rows][128 k] bf16, XOR-swizzled
    const int kc = blockIdx.x;   // 0..127
    const int t = threadIdx.x;   // 0..1023

    // stage: 4096 float4 chunks, 4 per thread, convert to bf16
    #pragma unroll
    for (int rep = 0; rep < 4; ++rep) {
        int ch = rep * 1024 + t;
        int row = ch >> 5, f4 = ch & 31;
        float4 w4 = *reinterpret_cast<const float4*>(
            W + (size_t)row * 16384 + kc * 128 + f4 * 4);
        ushort4 h = make_ushort4(f2bf(w4.x), f2bf(w4.y), f2bf(w4.z), f2bf(w4.w));
        *reinterpret_cast<ushort4*>(WS + row * 256 + ((f4 * 8) ^ ((row & 7) << 4))) = h;
    }
    __syncthreads();

    const int wid = t >> 6, l = t & 63;
    const int lr = l & 31, lhi = l >> 5;
    const int r = wid >> 2;              // output row-tile 0..3
    const int c = wid & 3;               // output col-tile 0..3

    f32x16 acc;
    #pragma unroll
    for (int i = 0; i < 16; ++i) acc[i] = 0.f;

    const int arow = r * 32 + lr;
    const int brow = c * 32 + lr;
    #pragma unroll
    for (int kk = 0; kk < 8; ++kk) {
        int kb = kk * 32 + lhi * 16;
        s16x8 a = *reinterpret_cast<const s16x8*>(WS + arow * 256 + (kb ^ ((arow & 7) << 4)));
        s16x8 bb = *reinterpret_cast<const s16x8*>(WS + brow * 256 + (kb ^ ((brow & 7) << 4)));
        acc = __builtin_amdgcn_mfma_f32_32x32x16_bf16(a, bb, acc, 0, 0, 0);
    }

    unsigned short* gp = gpart + (size_t)kc * 16384;
    #pragma unroll
    for (int reg = 0; reg < 16; ++reg) {
        int row = r * 32 + (reg & 3) + 8 * (reg >> 2) + 4 * lhi;
        __builtin_nontemporal_store(f2bf(acc[reg]), gp + row * 128 + c * 32 + lr);
    }
}

// ---------------------------------------------------------------------------
// Kernel 2: blocks 0..127 reduce bf16 partials -> Gh (bf16); 128..129 trace.
// ---------------------------------------------------------------------------
__global__ __launch_bounds__(256) void k_gred(const unsigned short* __restrict__ gpart,
                                              const float* __restrict__ W,
                                              unsigned short* __restrict__ Gh,
                                              float* __restrict__ tvec) {
    __shared__ float red[256];
    const int blk = blockIdx.x;
    const int t = threadIdx.x;

    if (blk < 128) {
        const int oo = t & 127, cg = t >> 7;
        const size_t o = (size_t)blk * 128 + oo;
        float s = 0.f;
        for (int ch = cg * 64; ch < cg * 64 + 64; ++ch)
            s += bf2f(gpart[(size_t)ch * 16384 + o]);
        red[t] = s;
        __syncthreads();
        if (t < 128) Gh[o] = f2bf(red[t] + red[t + 128]);
    } else {
        const int iloc = t >> 2, q = t & 3;
        const int i = (blk - 128) * 64 + iloc;
        float s = 0.f;
        for (int a = q * 32; a < q * 32 + 32; ++a)
            s += W[(size_t)i * 16384 + a * 129];
        red[t] = s;
        __syncthreads();
        if (q == 0)
            tvec[i] = red[iloc * 4] + red[iloc * 4 + 1] +
                      red[iloc * 4 + 2] + red[iloc * 4 + 3];
    }
}

// ---------------------------------------------------------------------------
// Kernel 3 (fused pv+den): one block per batch b, 512 threads (8 waves).
//   Y = Xb G (8 tiles / 8 waves) -> YS
//   P = (Y Xb^T)*scale (4 tiles / 4 waves) -> PS + global; v, mask on others
//   denominator from PS in LDS -> stat[b] = 1/sum
// LDS ~ 81 KiB.
// ---------------------------------------------------------------------------
__global__ __launch_bounds__(512) void k_pvd(const float* __restrict__ x,
                                             const unsigned short* __restrict__ Gh,
                                             const float* __restrict__ tvec,
                                             const float* __restrict__ seq,
                                             float* __restrict__ P,
                                             float* __restrict__ V,
                                             float* __restrict__ stat) {
    __shared__ char XS[16384];   // [64 jets][128] bf16 swz
    __shared__ char GS[32768];   // [128][128] bf16 swz (G symmetric)
    __shared__ char YS[16384];   // [64 rows][128] bf16 swz
    __shared__ float PS[64 * 64];
    __shared__ float ts[128];
    __shared__ float vls[64];
    __shared__ int   flg[64];
    __shared__ float wred[8];
    const int b = blockIdx.x;
    const int t = threadIdx.x;   // 0..511

    // stage Xb: 2048 float4, 4/thread
    #pragma unroll
    for (int rep = 0; rep < 4; ++rep) {
        int ch = rep * 512 + t;
        int row = ch >> 5, f4 = ch & 31;
        float4 x4 = *reinterpret_cast<const float4*>(
            x + (size_t)row * 16384 + b * 128 + f4 * 4);
        ushort4 h = make_ushort4(f2bf(x4.x), f2bf(x4.y), f2bf(x4.z), f2bf(x4.w));
        *reinterpret_cast<ushort4*>(XS + row * 256 + ((f4 * 8) ^ ((row & 7) << 4))) = h;
    }
    // stage Gh: 2048 16B chunks, 4/thread
    #pragma unroll
    for (int rep = 0; rep < 4; ++rep) {
        int ch = rep * 512 + t;
        int row = ch >> 4, kb = ch & 15;
        uint4 g4 = *reinterpret_cast<const uint4*>(Gh + row * 128 + kb * 8);
        *reinterpret_cast<uint4*>(GS + row * 256 + ((kb * 16) ^ ((row & 7) << 4))) = g4;
    }
    if (t < 128) ts[t] = tvec[t];
    __syncthreads();

    const int wid = t >> 6, l = t & 63, lr = l & 31, lhi = l >> 5;

    // ---- Y: wave wid -> tile (yr = wid>>2, yc = wid&3)
    {
        f32x16 acc;
        #pragma unroll
        for (int i = 0; i < 16; ++i) acc[i] = 0.f;
        const int arow = (wid >> 2) * 32 + lr;   // jet row
        const int brow = (wid & 3) * 32 + lr;    // G row (== col, symmetric)
        #pragma unroll
        for (int kk = 0; kk < 8; ++kk) {
            int kb = kk * 32 + lhi * 16;
            s16x8 a = *reinterpret_cast<const s16x8*>(XS + arow * 256 + (kb ^ ((arow & 7) << 4)));
            s16x8 g = *reinterpret_cast<const s16x8*>(GS + brow * 256 + (kb ^ ((brow & 7) << 4)));
            acc = __builtin_amdgcn_mfma_f32_32x32x16_bf16(a, g, acc, 0, 0, 0);
        }
        #pragma unroll
        for (int reg = 0; reg < 16; ++reg) {
            int row = (wid >> 2) * 32 + (reg & 3) + 8 * (reg >> 2) + 4 * lhi;
            int col = (wid & 3) * 32 + lr;
            *reinterpret_cast<unsigned short*>(
                YS + row * 256 + ((2 * col) ^ ((row & 7) << 4))) = f2bf(acc[reg]);
        }
    }
    __syncthreads();

    // ---- P (waves 0..3), v (wave 4), mask (wave 5)
    if (wid < 4) {
        f32x16 pa;
        #pragma unroll
        for (int i = 0; i < 16; ++i) pa[i] = 0.f;
        const int arow = (wid >> 1) * 32 + lr;   // Y row (n)
        const int brow = (wid & 1) * 32 + lr;    // jet m
        #pragma unroll
        for (int kk = 0; kk < 8; ++kk) {
            int kb = kk * 32 + lhi * 16;
            s16x8 a = *reinterpret_cast<const s16x8*>(YS + arow * 256 + (kb ^ ((arow & 7) << 4)));
            s16x8 bb = *reinterpret_cast<const s16x8*>(XS + brow * 256 + (kb ^ ((brow & 7) << 4)));
            pa = __builtin_amdgcn_mfma_f32_32x32x16_bf16(a, bb, pa, 0, 0, 0);
        }
        const float SCALE = 1.0f / (128.0f * 128.0f * sqrtf(128.0f));
        #pragma unroll
        for (int reg = 0; reg < 16; ++reg) {
            int n = (wid >> 1) * 32 + (reg & 3) + 8 * (reg >> 2) + 4 * lhi;
            int m = (wid & 1) * 32 + lr;
            float pv = pa[reg] * SCALE;
            PS[n * 64 + m] = pv;
            P[(size_t)b * 4096 + n * 64 + m] = pv;
        }
    } else if (wid == 4) {
        // v[l] = sum_i Xb[l][i] * t[i]
        float s = 0.f;
        #pragma unroll
        for (int kb = 0; kb < 16; ++kb) {
            uint4 c4 = *reinterpret_cast<const uint4*>(
                XS + l * 256 + ((kb * 16) ^ ((l & 7) << 4)));
            const unsigned short* hp = reinterpret_cast<const unsigned short*>(&c4);
            #pragma unroll
            for (int e = 0; e < 8; ++e)
                s += bf2f(hp[e]) * ts[kb * 8 + e];
        }
        vls[l] = s;
        V[b * 64 + l] = s;
    } else if (wid == 5) {
        flg[l] = (seq[l * NB + b] > 0.f) ? 1 : 0;
    }
    __syncthreads();

    // ---- denominator: thread t handles 8 entries (n = t>>3, m = (t&7)*8+j)
    const int n = t >> 3;
    const int m0 = (t & 7) * 8;
    float a[8];
    int ok[8];
    const int fln = flg[n];
    #pragma unroll
    for (int j = 0; j < 8; ++j) {
        a[j] = PS[n * 64 + m0 + j];
        ok[j] = fln && flg[m0 + j] && (n != (m0 + j));
    }
    float s = 0.f;
    for (int ll = 0; ll < 64; ++ll) {
        if (!flg[ll]) continue;
        float vv = vls[ll];
        #pragma unroll
        for (int j = 0; j < 8; ++j)
            s += ok[j] ? __expf(a[j] * vv) : 0.f;
    }
    #pragma unroll
    for (int j = 0; j < 8; ++j)
        if (ok[j])
            s -= __expf(a[j] * vls[n]) + __expf(a[j] * vls[m0 + j]);

    #pragma unroll
    for (int off = 32; off > 0; off >>= 1) s += __shfl_down(s, off, 64);
    if (l == 0) wred[wid] = s;
    __syncthreads();
    if (t == 0) {
        float tot = wred[0] + wred[1] + wred[2] + wred[3] +
                    wred[4] + wred[5] + wred[6] + wred[7];
        stat[b] = 1.0f / tot;
    }
}

// ---------------------------------------------------------------------------
// Kernel 4: out[b,n,m,l] = mask * exp(P[n,m]*v[l]) * invden
// Wave stores are 1KB-contiguous; nontemporal (134 MB stream).
// ---------------------------------------------------------------------------
__global__ __launch_bounds__(256) void k_out(const float* __restrict__ P,
                                             const float* __restrict__ V,
                                             const float* __restrict__ seq,
                                             const float* __restrict__ stat,
                                             float* __restrict__ out) {
    __shared__ float vl[64];
    __shared__ int   fl[64];
    __shared__ float prow[64];
    __shared__ float sinv_s;
    const int n = blockIdx.x;   // 0..63
    const int b = blockIdx.y;   // 0..127
    const int t = threadIdx.x;

    if (t < 64) {
        vl[t]   = V[b * 64 + t];
        fl[t]   = (seq[t * NB + b] > 0.f) ? 1 : 0;
        prow[t] = P[(size_t)b * 4096 + n * 64 + t];
    }
    if (t == 64) sinv_s = stat[b];
    __syncthreads();

    const int fln = fl[n];
    const float inv = sinv_s;
    float* slab = out + ((size_t)b << 18) + (n << 12);
    #pragma unroll
    for (int c = 0; c < 4; ++c) {
        int idx = c * 1024 + t * 4;
        int m = idx >> 6;
        int l0 = idx & 63;
        float a = prow[m];
        bool okm = fln && fl[m] && (m != n);
        f32x4 o;
        {
            int l = l0;
            o[0] = (okm && fl[l] && (l != n) && (l != m)) ? __expf(a * vl[l]) * inv : 0.f;
            l = l0 + 1;
            o[1] = (okm && fl[l] && (l != n) && (l != m)) ? __expf(a * vl[l]) * inv : 0.f;
            l = l0 + 2;
            o[2] = (okm && fl[l] && (l != n) && (l != m)) ? __expf(a * vl[l]) * inv : 0.f;
            l = l0 + 3;
            o[3] = (okm && fl[l] && (l != n) && (l != m)) ? __expf(a * vl[l]) * inv : 0.f;
        }
        __builtin_nontemporal_store(o, reinterpret_cast<f32x4*>(slab + idx));
    }
}

// ---------------------------------------------------------------------------
extern "C" void kernel_launch(void* const* d_in, const int* in_sizes, int n_in,
                              void* d_out, int out_size, void* d_ws, size_t ws_size,
                              hipStream_t stream) {
    const float* x   = (const float*)d_in[0];
    const float* seq = (const float*)d_in[1];
    const float* W   = (const float*)d_in[2];
    char* wsb = (char*)d_ws;
    unsigned short* gpart = (unsigned short*)(wsb + WSB_GPART);
    unsigned short* Gh    = (unsigned short*)(wsb + WSB_GH);
    float*          tvec  = (float*)(wsb + WSB_T);
    float*          P     = (float*)(wsb + WSB_P);
    float*          V     = (float*)(wsb + WSB_V);
    float*          stat  = (float*)(wsb + WSB_S);
    float* out = (float*)d_out;

    k_gram<<<128, 1024, 0, stream>>>(W, gpart);
    k_gred<<<130, 256, 0, stream>>>(gpart, W, Gh, tvec);
    k_pvd <<<128, 512, 0, stream>>>(x, Gh, tvec, seq, P, V, stat);
    k_out <<<dim3(64, 128), 256, 0, stream>>>(P, V, seq, stat, out);
}

// Round 6
// 79.462 us; speedup vs baseline: 1.5854x; 1.0320x over previous
//
#include <hip/hip_runtime.h>
#include <math.h>

#define NB 128     // BATCH

typedef short s16x8 __attribute__((ext_vector_type(8)));
typedef float f32x16 __attribute__((ext_vector_type(16)));
typedef float f32x4 __attribute__((ext_vector_type(4)));

// workspace layout (byte offsets, all >=512B aligned)
#define WSB_GPART 0u                       // 128 chunks * 16384 bf16 = 4 MB
#define WSB_GH    4194304u                 // 16384 bf16 = 32 KB
#define WSB_T     4227072u                 // 128 fp32
#define WSB_P     4227584u                 // 128*64*64 fp32 = 2 MB
#define WSB_V     6324736u                 // 128*64 fp32 = 32 KB
#define WSB_S     6357504u                 // 128 fp32

static __device__ __forceinline__ unsigned short f2bf(float f) {
    unsigned int u = __float_as_uint(f);
    return (unsigned short)((u + 0x7fffu + ((u >> 16) & 1u)) >> 16);
}
static __device__ __forceinline__ float bf2f(unsigned short h) {
    return __uint_as_float(((unsigned int)h) << 16);
}

// ---------------------------------------------------------------------------
// Kernel 1: blocks 0..127: gram partials via MFMA (G = Wf Wf^T, Wf=(128,16384),
// chunk = 128 k-cols, 16 waves = all 16 32x32 tiles, W read once).
// Blocks 128..129: trace vector t[i] = sum_a W[i,a,a].
// ---------------------------------------------------------------------------
__global__ __launch_bounds__(1024) void k_gram(const float* __restrict__ W,
                                               unsigned short* __restrict__ gpart,
                                               float* __restrict__ tvec) {
    __shared__ char WS[32768];   // [128 rows][128 k] bf16, XOR-swizzled
    const int blk = blockIdx.x;
    const int t = threadIdx.x;   // 0..1023

    if (blk >= 128) {
        // trace: 64 i per block, 16 lanes per i
        const int i = (blk - 128) * 64 + (t >> 4);
        const int a0 = (t & 15) * 8;
        float s = 0.f;
        #pragma unroll
        for (int a = a0; a < a0 + 8; ++a)
            s += W[(size_t)i * 16384 + a * 129];
        s += __shfl_down(s, 8, 16);
        s += __shfl_down(s, 4, 16);
        s += __shfl_down(s, 2, 16);
        s += __shfl_down(s, 1, 16);
        if ((t & 15) == 0) tvec[i] = s;
        return;
    }

    const int kc = blk;          // 0..127
    // stage: 4096 float4 chunks, 4 per thread, convert to bf16
    #pragma unroll
    for (int rep = 0; rep < 4; ++rep) {
        int ch = rep * 1024 + t;
        int row = ch >> 5, f4 = ch & 31;
        float4 w4 = *reinterpret_cast<const float4*>(
            W + (size_t)row * 16384 + kc * 128 + f4 * 4);
        ushort4 h = make_ushort4(f2bf(w4.x), f2bf(w4.y), f2bf(w4.z), f2bf(w4.w));
        *reinterpret_cast<ushort4*>(WS + row * 256 + ((f4 * 8) ^ ((row & 7) << 4))) = h;
    }
    __syncthreads();

    const int wid = t >> 6, l = t & 63;
    const int lr = l & 31, lhi = l >> 5;
    const int r = wid >> 2;              // output row-tile 0..3
    const int c = wid & 3;               // output col-tile 0..3

    f32x16 acc;
    #pragma unroll
    for (int i = 0; i < 16; ++i) acc[i] = 0.f;

    const int arow = r * 32 + lr;
    const int brow = c * 32 + lr;
    #pragma unroll
    for (int kk = 0; kk < 8; ++kk) {
        int kb = kk * 32 + lhi * 16;
        s16x8 a = *reinterpret_cast<const s16x8*>(WS + arow * 256 + (kb ^ ((arow & 7) << 4)));
        s16x8 bb = *reinterpret_cast<const s16x8*>(WS + brow * 256 + (kb ^ ((brow & 7) << 4)));
        acc = __builtin_amdgcn_mfma_f32_32x32x16_bf16(a, bb, acc, 0, 0, 0);
    }

    unsigned short* gp = gpart + (size_t)kc * 16384;
    #pragma unroll
    for (int reg = 0; reg < 16; ++reg) {
        int row = r * 32 + (reg & 3) + 8 * (reg >> 2) + 4 * lhi;
        gp[row * 128 + c * 32 + lr] = f2bf(acc[reg]);   // plain store: re-read next kernel
    }
}

// ---------------------------------------------------------------------------
// Kernel 2: reduce bf16 partials -> Gh (bf16).
// ---------------------------------------------------------------------------
__global__ __launch_bounds__(256) void k_gred(const unsigned short* __restrict__ gpart,
                                              unsigned short* __restrict__ Gh) {
    __shared__ float red[256];
    const int blk = blockIdx.x;
    const int t = threadIdx.x;

    const int oo = t & 127, cg = t >> 7;
    const size_t o = (size_t)blk * 128 + oo;
    float s = 0.f;
    for (int ch = cg * 64; ch < cg * 64 + 64; ++ch)
        s += bf2f(gpart[(size_t)ch * 16384 + o]);
    red[t] = s;
    __syncthreads();
    if (t < 128) Gh[o] = f2bf(red[t] + red[t + 128]);
}

// ---------------------------------------------------------------------------
// Kernel 3 (fused pv+den): one block per batch b, 512 threads (8 waves).
// ---------------------------------------------------------------------------
__global__ __launch_bounds__(512) void k_pvd(const float* __restrict__ x,
                                             const unsigned short* __restrict__ Gh,
                                             const float* __restrict__ tvec,
                                             const float* __restrict__ seq,
                                             float* __restrict__ P,
                                             float* __restrict__ V,
                                             float* __restrict__ stat) {
    __shared__ char XS[16384];   // [64 jets][128] bf16 swz
    __shared__ char GS[32768];   // [128][128] bf16 swz (G symmetric)
    __shared__ char YS[16384];   // [64 rows][128] bf16 swz
    __shared__ float PS[64 * 64];
    __shared__ float ts[128];
    __shared__ float vls[64];
    __shared__ int   flg[64];
    __shared__ float wred[8];
    const int b = blockIdx.x;
    const int t = threadIdx.x;   // 0..511

    // stage Xb: 2048 float4, 4/thread
    #pragma unroll
    for (int rep = 0; rep < 4; ++rep) {
        int ch = rep * 512 + t;
        int row = ch >> 5, f4 = ch & 31;
        float4 x4 = *reinterpret_cast<const float4*>(
            x + (size_t)row * 16384 + b * 128 + f4 * 4);
        ushort4 h = make_ushort4(f2bf(x4.x), f2bf(x4.y), f2bf(x4.z), f2bf(x4.w));
        *reinterpret_cast<ushort4*>(XS + row * 256 + ((f4 * 8) ^ ((row & 7) << 4))) = h;
    }
    // stage Gh: 2048 16B chunks, 4/thread
    #pragma unroll
    for (int rep = 0; rep < 4; ++rep) {
        int ch = rep * 512 + t;
        int row = ch >> 4, kb = ch & 15;
        uint4 g4 = *reinterpret_cast<const uint4*>(Gh + row * 128 + kb * 8);
        *reinterpret_cast<uint4*>(GS + row * 256 + ((kb * 16) ^ ((row & 7) << 4))) = g4;
    }
    if (t < 128) ts[t] = tvec[t];
    __syncthreads();

    const int wid = t >> 6, l = t & 63, lr = l & 31, lhi = l >> 5;

    // ---- Y: wave wid -> tile (yr = wid>>2, yc = wid&3)
    {
        f32x16 acc;
        #pragma unroll
        for (int i = 0; i < 16; ++i) acc[i] = 0.f;
        const int arow = (wid >> 2) * 32 + lr;   // jet row
        const int brow = (wid & 3) * 32 + lr;    // G row (== col, symmetric)
        #pragma unroll
        for (int kk = 0; kk < 8; ++kk) {
            int kb = kk * 32 + lhi * 16;
            s16x8 a = *reinterpret_cast<const s16x8*>(XS + arow * 256 + (kb ^ ((arow & 7) << 4)));
            s16x8 g = *reinterpret_cast<const s16x8*>(GS + brow * 256 + (kb ^ ((brow & 7) << 4)));
            acc = __builtin_amdgcn_mfma_f32_32x32x16_bf16(a, g, acc, 0, 0, 0);
        }
        #pragma unroll
        for (int reg = 0; reg < 16; ++reg) {
            int row = (wid >> 2) * 32 + (reg & 3) + 8 * (reg >> 2) + 4 * lhi;
            int col = (wid & 3) * 32 + lr;
            *reinterpret_cast<unsigned short*>(
                YS + row * 256 + ((2 * col) ^ ((row & 7) << 4))) = f2bf(acc[reg]);
        }
    }
    __syncthreads();

    // ---- P (waves 0..3), v (wave 4), mask (wave 5)
    if (wid < 4) {
        f32x16 pa;
        #pragma unroll
        for (int i = 0; i < 16; ++i) pa[i] = 0.f;
        const int arow = (wid >> 1) * 32 + lr;   // Y row (n)
        const int brow = (wid & 1) * 32 + lr;    // jet m
        #pragma unroll
        for (int kk = 0; kk < 8; ++kk) {
            int kb = kk * 32 + lhi * 16;
            s16x8 a = *reinterpret_cast<const s16x8*>(YS + arow * 256 + (kb ^ ((arow & 7) << 4)));
            s16x8 bb = *reinterpret_cast<const s16x8*>(XS + brow * 256 + (kb ^ ((brow & 7) << 4)));
            pa = __builtin_amdgcn_mfma_f32_32x32x16_bf16(a, bb, pa, 0, 0, 0);
        }
        const float SCALE = 1.0f / (128.0f * 128.0f * sqrtf(128.0f));
        #pragma unroll
        for (int reg = 0; reg < 16; ++reg) {
            int n = (wid >> 1) * 32 + (reg & 3) + 8 * (reg >> 2) + 4 * lhi;
            int m = (wid & 1) * 32 + lr;
            float pv = pa[reg] * SCALE;
            PS[n * 64 + m] = pv;
            P[(size_t)b * 4096 + n * 64 + m] = pv;
        }
    } else if (wid == 4) {
        // v[l] = sum_i Xb[l][i] * t[i]
        float s = 0.f;
        #pragma unroll
        for (int kb = 0; kb < 16; ++kb) {
            uint4 c4 = *reinterpret_cast<const uint4*>(
                XS + l * 256 + ((kb * 16) ^ ((l & 7) << 4)));
            const unsigned short* hp = reinterpret_cast<const unsigned short*>(&c4);
            #pragma unroll
            for (int e = 0; e < 8; ++e)
                s += bf2f(hp[e]) * ts[kb * 8 + e];
        }
        vls[l] = s;
        V[b * 64 + l] = s;
    } else if (wid == 5) {
        flg[l] = (seq[l * NB + b] > 0.f) ? 1 : 0;
    }
    __syncthreads();

    // ---- denominator: thread t handles 8 entries (n = t>>3, m = (t&7)*8+j)
    const int n = t >> 3;
    const int m0 = (t & 7) * 8;
    float a[8];
    int ok[8];
    const int fln = flg[n];
    int anyok = 0;
    #pragma unroll
    for (int j = 0; j < 8; ++j) {
        a[j] = PS[n * 64 + m0 + j];
        ok[j] = fln && flg[m0 + j] && (n != (m0 + j));
        anyok |= ok[j];
    }
    float s = 0.f;
    if (__any(anyok)) {          // skip whole exp loop for fully-masked waves
        for (int ll = 0; ll < 64; ++ll) {
            if (!flg[ll]) continue;
            float vv = vls[ll];
            #pragma unroll
            for (int j = 0; j < 8; ++j)
                s += ok[j] ? __expf(a[j] * vv) : 0.f;
        }
        #pragma unroll
        for (int j = 0; j < 8; ++j)
            if (ok[j])
                s -= __expf(a[j] * vls[n]) + __expf(a[j] * vls[m0 + j]);
    }

    #pragma unroll
    for (int off = 32; off > 0; off >>= 1) s += __shfl_down(s, off, 64);
    if (l == 0) wred[wid] = s;
    __syncthreads();
    if (t == 0) {
        float tot = wred[0] + wred[1] + wred[2] + wred[3] +
                    wred[4] + wred[5] + wred[6] + wred[7];
        stat[b] = 1.0f / tot;
    }
}

// ---------------------------------------------------------------------------
// Kernel 4: out[b,n,m,l] = mask * exp(P[n,m]*v[l]) * invden
// Block (bx, b): 4 n-slabs (n = bx*4 + t>>8), 1024 threads. Zero fast path
// for invalid n. 1KB-contiguous NT wave stores (134 MB stream).
// ---------------------------------------------------------------------------
__global__ __launch_bounds__(1024) void k_out(const float* __restrict__ P,
                                              const float* __restrict__ V,
                                              const float* __restrict__ seq,
                                              const float* __restrict__ stat,
                                              float* __restrict__ out) {
    __shared__ float vl[64];
    __shared__ int   fl[64];
    __shared__ float prow[256];
    __shared__ float sinv_s;
    const int bx = blockIdx.x;  // 0..15
    const int b  = blockIdx.y;  // 0..127
    const int t = threadIdx.x;  // 0..1023

    if (t < 64) {
        vl[t] = V[b * 64 + t];
        fl[t] = (seq[t * NB + b] > 0.f) ? 1 : 0;
    } else if (t < 320) {
        int q = t - 64;               // 0..255: 4 rows x 64 cols
        prow[q] = P[(size_t)b * 4096 + (bx * 4 + (q >> 6)) * 64 + (q & 63)];
    } else if (t == 320) {
        sinv_s = stat[b];
    }
    __syncthreads();

    const int slab = t >> 8;          // 0..3 (wave-uniform)
    const int tt = t & 255;
    const int n = bx * 4 + slab;
    float* slabp = out + ((size_t)b << 18) + ((size_t)n << 12);

    if (!fl[n]) {
        f32x4 z = {0.f, 0.f, 0.f, 0.f};
        #pragma unroll
        for (int c = 0; c < 4; ++c)
            __builtin_nontemporal_store(z, reinterpret_cast<f32x4*>(slabp + c * 1024 + tt * 4));
        return;
    }

    const float inv = sinv_s;
    #pragma unroll
    for (int c = 0; c < 4; ++c) {
        int idx = c * 1024 + tt * 4;
        int m = idx >> 6;
        int l0 = idx & 63;
        float a = prow[slab * 64 + m];
        bool okm = fl[m] && (m != n);
        f32x4 o;
        #pragma unroll
        for (int j = 0; j < 4; ++j) {
            int l = l0 + j;
            o[j] = (okm && fl[l] && (l != n) && (l != m)) ? __expf(a * vl[l]) * inv : 0.f;
        }
        __builtin_nontemporal_store(o, reinterpret_cast<f32x4*>(slabp + idx));
    }
}

// ---------------------------------------------------------------------------
extern "C" void kernel_launch(void* const* d_in, const int* in_sizes, int n_in,
                              void* d_out, int out_size, void* d_ws, size_t ws_size,
                              hipStream_t stream) {
    const float* x   = (const float*)d_in[0];
    const float* seq = (const float*)d_in[1];
    const float* W   = (const float*)d_in[2];
    char* wsb = (char*)d_ws;
    unsigned short* gpart = (unsigned short*)(wsb + WSB_GPART);
    unsigned short* Gh    = (unsigned short*)(wsb + WSB_GH);
    float*          tvec  = (float*)(wsb + WSB_T);
    float*          P     = (float*)(wsb + WSB_P);
    float*          V     = (float*)(wsb + WSB_V);
    float*          stat  = (float*)(wsb + WSB_S);
    float* out = (float*)d_out;

    k_gram<<<130, 1024, 0, stream>>>(W, gpart, tvec);
    k_gred<<<128, 256, 0, stream>>>(gpart, Gh);
    k_pvd <<<128, 512, 0, stream>>>(x, Gh, tvec, seq, P, V, stat);
    k_out <<<dim3(16, 128), 1024, 0, stream>>>(P, V, seq, stat, out);
}

// Round 7
// 58.101 us; speedup vs baseline: 2.1683x; 1.3676x over previous
//
#include <hip/hip_runtime.h>
#include <math.h>

#define NB 128     // BATCH

typedef short s16x8 __attribute__((ext_vector_type(8)));
typedef float f32x16 __attribute__((ext_vector_type(16)));
typedef float f32x4 __attribute__((ext_vector_type(4)));

// workspace layout (byte offsets, all >=512B aligned)
#define WSB_GPART 0u                       // 128 chunks * 16384 bf16 = 4 MB
#define WSB_GH    4194304u                 // 16384 bf16 = 32 KB
#define WSB_T     4227072u                 // 128 fp32
#define WSB_P     4227584u                 // 128*64*64 fp32 = 2 MB
#define WSB_V     6324736u                 // 128*64 fp32 = 32 KB
#define WSB_S     6357504u                 // 128*2 fp32 (den partials)

static __device__ __forceinline__ unsigned short f2bf(float f) {
    unsigned int u = __float_as_uint(f);
    return (unsigned short)((u + 0x7fffu + ((u >> 16) & 1u)) >> 16);
}
static __device__ __forceinline__ float bf2f(unsigned short h) {
    return __uint_as_float(((unsigned int)h) << 16);
}

// ---------------------------------------------------------------------------
// Kernel 1: blocks 0..127: gram partials via MFMA (G = Wf Wf^T, Wf=(128,16384),
// chunk = 128 k-cols, 16 waves = all 16 32x32 tiles, W read once).
// Blocks 128..129: trace vector t[i] = sum_a W[i,a,a].
// ---------------------------------------------------------------------------
__global__ __launch_bounds__(1024) void k_gram(const float* __restrict__ W,
                                               unsigned short* __restrict__ gpart,
                                               float* __restrict__ tvec) {
    __shared__ char WS[32768];   // [128 rows][128 k] bf16, XOR-swizzled
    const int blk = blockIdx.x;
    const int t = threadIdx.x;   // 0..1023

    if (blk >= 128) {
        // trace: 64 i per block, 16 lanes per i
        const int i = (blk - 128) * 64 + (t >> 4);
        const int a0 = (t & 15) * 8;
        float s = 0.f;
        #pragma unroll
        for (int a = a0; a < a0 + 8; ++a)
            s += W[(size_t)i * 16384 + a * 129];
        s += __shfl_down(s, 8, 16);
        s += __shfl_down(s, 4, 16);
        s += __shfl_down(s, 2, 16);
        s += __shfl_down(s, 1, 16);
        if ((t & 15) == 0) tvec[i] = s;
        return;
    }

    const int kc = blk;          // 0..127
    // stage: 4096 float4 chunks, 4 per thread, convert to bf16
    #pragma unroll
    for (int rep = 0; rep < 4; ++rep) {
        int ch = rep * 1024 + t;
        int row = ch >> 5, f4 = ch & 31;
        float4 w4 = *reinterpret_cast<const float4*>(
            W + (size_t)row * 16384 + kc * 128 + f4 * 4);
        ushort4 h = make_ushort4(f2bf(w4.x), f2bf(w4.y), f2bf(w4.z), f2bf(w4.w));
        *reinterpret_cast<ushort4*>(WS + row * 256 + ((f4 * 8) ^ ((row & 7) << 4))) = h;
    }
    __syncthreads();

    const int wid = t >> 6, l = t & 63;
    const int lr = l & 31, lhi = l >> 5;
    const int r = wid >> 2;              // output row-tile 0..3
    const int c = wid & 3;               // output col-tile 0..3

    f32x16 acc;
    #pragma unroll
    for (int i = 0; i < 16; ++i) acc[i] = 0.f;

    const int arow = r * 32 + lr;
    const int brow = c * 32 + lr;
    #pragma unroll
    for (int kk = 0; kk < 8; ++kk) {
        int kb = kk * 32 + lhi * 16;
        s16x8 a = *reinterpret_cast<const s16x8*>(WS + arow * 256 + (kb ^ ((arow & 7) << 4)));
        s16x8 bb = *reinterpret_cast<const s16x8*>(WS + brow * 256 + (kb ^ ((brow & 7) << 4)));
        acc = __builtin_amdgcn_mfma_f32_32x32x16_bf16(a, bb, acc, 0, 0, 0);
    }

    unsigned short* gp = gpart + (size_t)kc * 16384;
    #pragma unroll
    for (int reg = 0; reg < 16; ++reg) {
        int row = r * 32 + (reg & 3) + 8 * (reg >> 2) + 4 * lhi;
        gp[row * 128 + c * 32 + lr] = f2bf(acc[reg]);
    }
}

// ---------------------------------------------------------------------------
// Kernel 2: reduce bf16 partials -> Gh. Block owns 128 outputs; thread
// (og = t&15 -> 8 outputs, cg = t>>4 -> 8 chunks) does 8 uint4 loads
// (independent, pipelined), then 2-stage LDS reduce.
// ---------------------------------------------------------------------------
__global__ __launch_bounds__(256) void k_gred(const unsigned short* __restrict__ gpart,
                                              unsigned short* __restrict__ Gh) {
    __shared__ float red[16 * 128];
    const int blk = blockIdx.x;      // 0..127
    const int t = threadIdx.x;       // 0..255
    const int og = t & 15;           // 8 consecutive outputs
    const int cg = t >> 4;           // 8 consecutive chunks

    float acc[8];
    #pragma unroll
    for (int e = 0; e < 8; ++e) acc[e] = 0.f;

    const unsigned short* base = gpart + blk * 128 + og * 8;
    #pragma unroll
    for (int c = 0; c < 8; ++c) {
        uint4 u = *reinterpret_cast<const uint4*>(base + (size_t)(cg * 8 + c) * 16384);
        const unsigned short* hp = reinterpret_cast<const unsigned short*>(&u);
        #pragma unroll
        for (int e = 0; e < 8; ++e) acc[e] += bf2f(hp[e]);
    }
    #pragma unroll
    for (int e = 0; e < 8; ++e) red[cg * 128 + og * 8 + e] = acc[e];
    __syncthreads();

    if (t < 128) {
        float s = 0.f;
        #pragma unroll
        for (int g = 0; g < 16; ++g) s += red[g * 128 + t];
        Gh[blk * 128 + t] = f2bf(s);
    }
}

// ---------------------------------------------------------------------------
// Kernel 3 (fused pv+den): block (b, nh) -> 32 n-rows. 512 threads (8 waves).
//   Y[32x128] = Xb[nh rows] G (4 tiles / waves 0-3) -> YS
//   P[32x64] = (Y Xb^T)*scale (2 tiles / waves 0-1) -> PS + global
//   v (wave 4, V written by nh==0), flags (wave 5)
//   partial denominator over n in this half -> stat2[b*2+nh]
// LDS ~ 66 KiB -> 2 blocks/CU.
// ---------------------------------------------------------------------------
__global__ __launch_bounds__(512) void k_pvd(const float* __restrict__ x,
                                             const unsigned short* __restrict__ Gh,
                                             const float* __restrict__ tvec,
                                             const float* __restrict__ seq,
                                             float* __restrict__ P,
                                             float* __restrict__ V,
                                             float* __restrict__ stat2) {
    __shared__ char XS[16384];   // [64 jets][128] bf16 swz
    __shared__ char GS[32768];   // [128][128] bf16 swz (G symmetric)
    __shared__ char YS[8192];    // [32 rows][128] bf16 swz
    __shared__ float PS[32 * 64];
    __shared__ float ts[128];
    __shared__ float vls[64];
    __shared__ int   flg[64];
    __shared__ float wred[8];
    const int b  = blockIdx.x;
    const int nh = blockIdx.y;   // 0..1
    const int t = threadIdx.x;   // 0..511

    // stage Xb: 2048 float4, 4/thread
    #pragma unroll
    for (int rep = 0; rep < 4; ++rep) {
        int ch = rep * 512 + t;
        int row = ch >> 5, f4 = ch & 31;
        float4 x4 = *reinterpret_cast<const float4*>(
            x + (size_t)row * 16384 + b * 128 + f4 * 4);
        ushort4 h = make_ushort4(f2bf(x4.x), f2bf(x4.y), f2bf(x4.z), f2bf(x4.w));
        *reinterpret_cast<ushort4*>(XS + row * 256 + ((f4 * 8) ^ ((row & 7) << 4))) = h;
    }
    // stage Gh: 2048 16B chunks, 4/thread
    #pragma unroll
    for (int rep = 0; rep < 4; ++rep) {
        int ch = rep * 512 + t;
        int row = ch >> 4, kb = ch & 15;
        uint4 g4 = *reinterpret_cast<const uint4*>(Gh + row * 128 + kb * 8);
        *reinterpret_cast<uint4*>(GS + row * 256 + ((kb * 16) ^ ((row & 7) << 4))) = g4;
    }
    if (t < 128) ts[t] = tvec[t];
    __syncthreads();

    const int wid = t >> 6, l = t & 63, lr = l & 31, lhi = l >> 5;

    // ---- Y (waves 0-3: col-tile wid), v (wave 4), flags (wave 5)
    if (wid < 4) {
        f32x16 acc;
        #pragma unroll
        for (int i = 0; i < 16; ++i) acc[i] = 0.f;
        const int arow = nh * 32 + lr;       // jet row
        const int brow = wid * 32 + lr;      // G row (== col, symmetric)
        #pragma unroll
        for (int kk = 0; kk < 8; ++kk) {
            int kb = kk * 32 + lhi * 16;
            s16x8 a = *reinterpret_cast<const s16x8*>(XS + arow * 256 + (kb ^ ((arow & 7) << 4)));
            s16x8 g = *reinterpret_cast<const s16x8*>(GS + brow * 256 + (kb ^ ((brow & 7) << 4)));
            acc = __builtin_amdgcn_mfma_f32_32x32x16_bf16(a, g, acc, 0, 0, 0);
        }
        #pragma unroll
        for (int reg = 0; reg < 16; ++reg) {
            int row = (reg & 3) + 8 * (reg >> 2) + 4 * lhi;   // local 0..31
            int col = wid * 32 + lr;
            *reinterpret_cast<unsigned short*>(
                YS + row * 256 + ((2 * col) ^ ((row & 7) << 4))) = f2bf(acc[reg]);
        }
    } else if (wid == 4) {
        // v[l] = sum_i Xb[l][i] * t[i]  (both halves compute; nh==0 writes V)
        float s = 0.f;
        #pragma unroll
        for (int kb = 0; kb < 16; ++kb) {
            uint4 c4 = *reinterpret_cast<const uint4*>(
                XS + l * 256 + ((kb * 16) ^ ((l & 7) << 4)));
            const unsigned short* hp = reinterpret_cast<const unsigned short*>(&c4);
            #pragma unroll
            for (int e = 0; e < 8; ++e)
                s += bf2f(hp[e]) * ts[kb * 8 + e];
        }
        vls[l] = s;
        if (nh == 0) V[b * 64 + l] = s;
    } else if (wid == 5) {
        flg[l] = (seq[l * NB + b] > 0.f) ? 1 : 0;
    }
    __syncthreads();

    // ---- P (waves 0-1: m-half wid), K = 128 over Y cols
    if (wid < 2) {
        f32x16 pa;
        #pragma unroll
        for (int i = 0; i < 16; ++i) pa[i] = 0.f;
        const int arow = lr;                 // YS local row
        const int brow = wid * 32 + lr;      // jet m
        #pragma unroll
        for (int kk = 0; kk < 8; ++kk) {
            int kb = kk * 32 + lhi * 16;
            s16x8 a = *reinterpret_cast<const s16x8*>(YS + arow * 256 + (kb ^ ((arow & 7) << 4)));
            s16x8 bb = *reinterpret_cast<const s16x8*>(XS + brow * 256 + (kb ^ ((brow & 7) << 4)));
            pa = __builtin_amdgcn_mfma_f32_32x32x16_bf16(a, bb, pa, 0, 0, 0);
        }
        const float SCALE = 1.0f / (128.0f * 128.0f * sqrtf(128.0f));
        #pragma unroll
        for (int reg = 0; reg < 16; ++reg) {
            int nl = (reg & 3) + 8 * (reg >> 2) + 4 * lhi;    // local n 0..31
            int m = wid * 32 + lr;
            float pv = pa[reg] * SCALE;
            PS[nl * 64 + m] = pv;
            P[(size_t)b * 4096 + (nh * 32 + nl) * 64 + m] = pv;
        }
    }
    __syncthreads();

    // ---- partial denominator: thread t -> (nl = t>>4, m = (t&15)*4 + j)
    const int nl = t >> 4;
    const int n = nh * 32 + nl;
    const int m0 = (t & 15) * 4;
    float a[4];
    int ok[4];
    const int fln = flg[n];
    int anyok = 0;
    #pragma unroll
    for (int j = 0; j < 4; ++j) {
        a[j] = PS[nl * 64 + m0 + j];
        ok[j] = fln && flg[m0 + j] && (n != (m0 + j));
        anyok |= ok[j];
    }
    float s = 0.f;
    if (__any(anyok)) {
        for (int ll = 0; ll < 64; ++ll) {
            if (!flg[ll]) continue;
            float vv = vls[ll];
            #pragma unroll
            for (int j = 0; j < 4; ++j)
                s += ok[j] ? __expf(a[j] * vv) : 0.f;
        }
        #pragma unroll
        for (int j = 0; j < 4; ++j)
            if (ok[j])
                s -= __expf(a[j] * vls[n]) + __expf(a[j] * vls[m0 + j]);
    }

    #pragma unroll
    for (int off = 32; off > 0; off >>= 1) s += __shfl_down(s, off, 64);
    if (l == 0) wred[wid] = s;
    __syncthreads();
    if (t == 0) {
        stat2[b * 2 + nh] = wred[0] + wred[1] + wred[2] + wred[3] +
                            wred[4] + wred[5] + wred[6] + wred[7];
    }
}

// ---------------------------------------------------------------------------
// Kernel 4: out[b,n,m,l] = mask * exp(P[n,m]*v[l]) / (s0+s1)
// Block (bx, b): 4 n-slabs, 1024 threads, zero fast path, NT f32x4 stores.
// ---------------------------------------------------------------------------
__global__ __launch_bounds__(1024) void k_out(const float* __restrict__ P,
                                              const float* __restrict__ V,
                                              const float* __restrict__ seq,
                                              const float* __restrict__ stat2,
                                              float* __restrict__ out) {
    __shared__ float vl[64];
    __shared__ int   fl[64];
    __shared__ float prow[256];
    __shared__ float sinv_s;
    const int bx = blockIdx.x;  // 0..15
    const int b  = blockIdx.y;  // 0..127
    const int t = threadIdx.x;  // 0..1023

    if (t < 64) {
        vl[t] = V[b * 64 + t];
        fl[t] = (seq[t * NB + b] > 0.f) ? 1 : 0;
    } else if (t < 320) {
        int q = t - 64;               // 0..255: 4 rows x 64 cols
        prow[q] = P[(size_t)b * 4096 + (bx * 4 + (q >> 6)) * 64 + (q & 63)];
    } else if (t == 320) {
        sinv_s = 1.0f / (stat2[b * 2] + stat2[b * 2 + 1]);
    }
    __syncthreads();

    const int slab = t >> 8;          // 0..3 (wave-uniform)
    const int tt = t & 255;
    const int n = bx * 4 + slab;
    float* slabp = out + ((size_t)b << 18) + ((size_t)n << 12);

    if (!fl[n]) {
        f32x4 z = {0.f, 0.f, 0.f, 0.f};
        #pragma unroll
        for (int c = 0; c < 4; ++c)
            __builtin_nontemporal_store(z, reinterpret_cast<f32x4*>(slabp + c * 1024 + tt * 4));
        return;
    }

    const float inv = sinv_s;
    #pragma unroll
    for (int c = 0; c < 4; ++c) {
        int idx = c * 1024 + tt * 4;
        int m = idx >> 6;
        int l0 = idx & 63;
        float a = prow[slab * 64 + m];
        bool okm = fl[m] && (m != n);
        f32x4 o;
        #pragma unroll
        for (int j = 0; j < 4; ++j) {
            int l = l0 + j;
            o[j] = (okm && fl[l] && (l != n) && (l != m)) ? __expf(a * vl[l]) * inv : 0.f;
        }
        __builtin_nontemporal_store(o, reinterpret_cast<f32x4*>(slabp + idx));
    }
}

// ---------------------------------------------------------------------------
extern "C" void kernel_launch(void* const* d_in, const int* in_sizes, int n_in,
                              void* d_out, int out_size, void* d_ws, size_t ws_size,
                              hipStream_t stream) {
    const float* x   = (const float*)d_in[0];
    const float* seq = (const float*)d_in[1];
    const float* W   = (const float*)d_in[2];
    char* wsb = (char*)d_ws;
    unsigned short* gpart = (unsigned short*)(wsb + WSB_GPART);
    unsigned short* Gh    = (unsigned short*)(wsb + WSB_GH);
    float*          tvec  = (float*)(wsb + WSB_T);
    float*          P     = (float*)(wsb + WSB_P);
    float*          V     = (float*)(wsb + WSB_V);
    float*          stat2 = (float*)(wsb + WSB_S);
    float* out = (float*)d_out;

    k_gram<<<130, 1024, 0, stream>>>(W, gpart, tvec);
    k_gred<<<128, 256, 0, stream>>>(gpart, Gh);
    k_pvd <<<dim3(128, 2), 512, 0, stream>>>(x, Gh, tvec, seq, P, V, stat2);
    k_out <<<dim3(16, 128), 1024, 0, stream>>>(P, V, seq, stat2, out);
}

// Round 10
// 52.622 us; speedup vs baseline: 2.3941x; 1.1041x over previous
//
#include <hip/hip_runtime.h>
#include <math.h>

#define NB 128     // BATCH

typedef short s16x8 __attribute__((ext_vector_type(8)));
typedef float f32x16 __attribute__((ext_vector_type(16)));
typedef float f32x4 __attribute__((ext_vector_type(4)));

// workspace layout (byte offsets)
#define WSB_GPART 0u                       // 128 chunks * 16384 bf16 = 4 MB
#define WSB_GH    4194304u                 // 16384 bf16 = 32 KB
#define WSB_T     4227072u                 // 128 fp32

static __device__ __forceinline__ unsigned short f2bf(float f) {
    unsigned int u = __float_as_uint(f);
    return (unsigned short)((u + 0x7fffu + ((u >> 16) & 1u)) >> 16);
}
static __device__ __forceinline__ float bf2f(unsigned short h) {
    return __uint_as_float(((unsigned int)h) << 16);
}

// ---------------------------------------------------------------------------
// Kernel 1: blocks 0..127: gram partials via MFMA (G = Wf Wf^T, Wf=(128,16384),
// chunk = 128 k-cols, 16 waves = all 16 32x32 tiles, W read once).
// Blocks 128..129: trace vector t[i] = sum_a W[i,a,a].
// ---------------------------------------------------------------------------
__global__ __launch_bounds__(1024) void k_gram(const float* __restrict__ W,
                                               unsigned short* __restrict__ gpart,
                                               float* __restrict__ tvec) {
    __shared__ char WS[32768];   // [128 rows][128 k] bf16, XOR-swizzled
    const int blk = blockIdx.x;
    const int t = threadIdx.x;   // 0..1023

    if (blk >= 128) {
        const int i = (blk - 128) * 64 + (t >> 4);
        const int a0 = (t & 15) * 8;
        float s = 0.f;
        #pragma unroll
        for (int a = a0; a < a0 + 8; ++a)
            s += W[(size_t)i * 16384 + a * 129];
        s += __shfl_down(s, 8, 16);
        s += __shfl_down(s, 4, 16);
        s += __shfl_down(s, 2, 16);
        s += __shfl_down(s, 1, 16);
        if ((t & 15) == 0) tvec[i] = s;
        return;
    }

    const int kc = blk;          // 0..127
    #pragma unroll
    for (int rep = 0; rep < 4; ++rep) {
        int ch = rep * 1024 + t;
        int row = ch >> 5, f4 = ch & 31;
        float4 w4 = *reinterpret_cast<const float4*>(
            W + (size_t)row * 16384 + kc * 128 + f4 * 4);
        ushort4 h = make_ushort4(f2bf(w4.x), f2bf(w4.y), f2bf(w4.z), f2bf(w4.w));
        *reinterpret_cast<ushort4*>(WS + row * 256 + ((f4 * 8) ^ ((row & 7) << 4))) = h;
    }
    __syncthreads();

    const int wid = t >> 6, l = t & 63;
    const int lr = l & 31, lhi = l >> 5;
    const int r = wid >> 2;              // output row-tile 0..3
    const int c = wid & 3;               // output col-tile 0..3

    f32x16 acc;
    #pragma unroll
    for (int i = 0; i < 16; ++i) acc[i] = 0.f;

    const int arow = r * 32 + lr;
    const int brow = c * 32 + lr;
    #pragma unroll
    for (int kk = 0; kk < 8; ++kk) {
        int kb = kk * 32 + lhi * 16;
        s16x8 a = *reinterpret_cast<const s16x8*>(WS + arow * 256 + (kb ^ ((arow & 7) << 4)));
        s16x8 bb = *reinterpret_cast<const s16x8*>(WS + brow * 256 + (kb ^ ((brow & 7) << 4)));
        acc = __builtin_amdgcn_mfma_f32_32x32x16_bf16(a, bb, acc, 0, 0, 0);
    }

    unsigned short* gp = gpart + (size_t)kc * 16384;
    #pragma unroll
    for (int reg = 0; reg < 16; ++reg) {
        int row = r * 32 + (reg & 3) + 8 * (reg >> 2) + 4 * lhi;
        gp[row * 128 + c * 32 + lr] = f2bf(acc[reg]);
    }
}

// ---------------------------------------------------------------------------
// Kernel 2: reduce bf16 partials -> Gh. Block owns 128 outputs; thread
// (og = t&15 -> 8 outputs, cg = t>>4 -> 8 chunks) does 8 independent uint4
// loads, then 2-stage LDS reduce.
// ---------------------------------------------------------------------------
__global__ __launch_bounds__(256) void k_gred(const unsigned short* __restrict__ gpart,
                                              unsigned short* __restrict__ Gh) {
    __shared__ float red[16 * 128];
    const int blk = blockIdx.x;      // 0..127
    const int t = threadIdx.x;       // 0..255
    const int og = t & 15;
    const int cg = t >> 4;

    float acc[8];
    #pragma unroll
    for (int e = 0; e < 8; ++e) acc[e] = 0.f;

    const unsigned short* base = gpart + blk * 128 + og * 8;
    #pragma unroll
    for (int c = 0; c < 8; ++c) {
        uint4 u = *reinterpret_cast<const uint4*>(base + (size_t)(cg * 8 + c) * 16384);
        const unsigned short* hp = reinterpret_cast<const unsigned short*>(&u);
        #pragma unroll
        for (int e = 0; e < 8; ++e) acc[e] += bf2f(hp[e]);
    }
    #pragma unroll
    for (int e = 0; e < 8; ++e) red[cg * 128 + og * 8 + e] = acc[e];
    __syncthreads();

    if (t < 128) {
        float s = 0.f;
        #pragma unroll
        for (int g = 0; g < 16; ++g) s += red[g * 128 + t];
        Gh[blk * 128 + t] = f2bf(s);
    }
}

// ---------------------------------------------------------------------------
// Kernel 3 (fused pv+den+out): block (b, nh), 512 threads (8 waves).
//   Full Y = Xb G (8 tiles / 8 waves), full P = (Y Xb^T)*scale -> PS (LDS),
//   v (wave 4), flags (wave 5), FULL per-batch denominator (duplicated in
//   both nh blocks -> no cross-block dep), then write out slabs
//   n = nh*32..+31 directly from LDS. No P/V/stat global round-trip.
// ---------------------------------------------------------------------------
__global__ __launch_bounds__(512) void k_pvout(const float* __restrict__ x,
                                               const unsigned short* __restrict__ Gh,
                                               const float* __restrict__ tvec,
                                               const float* __restrict__ seq,
                                               float* __restrict__ out) {
    __shared__ char XS[16384];   // [64 jets][128] bf16 swz
    __shared__ char GS[32768];   // [128][128] bf16 swz (G symmetric)
    __shared__ char YS[16384];   // [64 rows][128] bf16 swz
    __shared__ float PS[64 * 64];
    __shared__ float ts[128];
    __shared__ float vls[64];
    __shared__ int   flg[64];
    __shared__ float wred[8];
    __shared__ float sinv_s;
    const int b  = blockIdx.x;   // 0..127
    const int nh = blockIdx.y;   // 0..1
    const int t = threadIdx.x;   // 0..511

    // stage Xb: 2048 float4, 4/thread
    #pragma unroll
    for (int rep = 0; rep < 4; ++rep) {
        int ch = rep * 512 + t;
        int row = ch >> 5, f4 = ch & 31;
        float4 x4 = *reinterpret_cast<const float4*>(
            x + (size_t)row * 16384 + b * 128 + f4 * 4);
        ushort4 h = make_ushort4(f2bf(x4.x), f2bf(x4.y), f2bf(x4.z), f2bf(x4.w));
        *reinterpret_cast<ushort4*>(XS + row * 256 + ((f4 * 8) ^ ((row & 7) << 4))) = h;
    }
    // stage Gh: 2048 16B chunks, 4/thread
    #pragma unroll
    for (int rep = 0; rep < 4; ++rep) {
        int ch = rep * 512 + t;
        int row = ch >> 4, kb = ch & 15;
        uint4 g4 = *reinterpret_cast<const uint4*>(Gh + row * 128 + kb * 8);
        *reinterpret_cast<uint4*>(GS + row * 256 + ((kb * 16) ^ ((row & 7) << 4))) = g4;
    }
    if (t < 128) ts[t] = tvec[t];
    __syncthreads();

    const int wid = t >> 6, l = t & 63, lr = l & 31, lhi = l >> 5;

    // ---- full Y: wave wid -> tile (row-tile wid>>2, col-tile wid&3)
    {
        f32x16 acc;
        #pragma unroll
        for (int i = 0; i < 16; ++i) acc[i] = 0.f;
        const int arow = (wid >> 2) * 32 + lr;
        const int brow = (wid & 3) * 32 + lr;
        #pragma unroll
        for (int kk = 0; kk < 8; ++kk) {
            int kb = kk * 32 + lhi * 16;
            s16x8 a = *reinterpret_cast<const s16x8*>(XS + arow * 256 + (kb ^ ((arow & 7) << 4)));
            s16x8 g = *reinterpret_cast<const s16x8*>(GS + brow * 256 + (kb ^ ((brow & 7) << 4)));
            acc = __builtin_amdgcn_mfma_f32_32x32x16_bf16(a, g, acc, 0, 0, 0);
        }
        #pragma unroll
        for (int reg = 0; reg < 16; ++reg) {
            int row = (wid >> 2) * 32 + (reg & 3) + 8 * (reg >> 2) + 4 * lhi;
            int col = (wid & 3) * 32 + lr;
            *reinterpret_cast<unsigned short*>(
                YS + row * 256 + ((2 * col) ^ ((row & 7) << 4))) = f2bf(acc[reg]);
        }
    }
    __syncthreads();

    // ---- full P (waves 0..3), v (wave 4), flags (wave 5)
    if (wid < 4) {
        f32x16 pa;
        #pragma unroll
        for (int i = 0; i < 16; ++i) pa[i] = 0.f;
        const int arow = (wid >> 1) * 32 + lr;   // Y row (n)
        const int brow = (wid & 1) * 32 + lr;    // jet m
        #pragma unroll
        for (int kk = 0; kk < 8; ++kk) {
            int kb = kk * 32 + lhi * 16;
            s16x8 a = *reinterpret_cast<const s16x8*>(YS + arow * 256 + (kb ^ ((arow & 7) << 4)));
            s16x8 bb = *reinterpret_cast<const s16x8*>(XS + brow * 256 + (kb ^ ((brow & 7) << 4)));
            pa = __builtin_amdgcn_mfma_f32_32x32x16_bf16(a, bb, pa, 0, 0, 0);
        }
        const float SCALE = 1.0f / (128.0f * 128.0f * sqrtf(128.0f));
        #pragma unroll
        for (int reg = 0; reg < 16; ++reg) {
            int n = (wid >> 1) * 32 + (reg & 3) + 8 * (reg >> 2) + 4 * lhi;
            int m = (wid & 1) * 32 + lr;
            PS[n * 64 + m] = pa[reg] * SCALE;
        }
    } else if (wid == 4) {
        float s = 0.f;
        #pragma unroll
        for (int kb = 0; kb < 16; ++kb) {
            uint4 c4 = *reinterpret_cast<const uint4*>(
                XS + l * 256 + ((kb * 16) ^ ((l & 7) << 4)));
            const unsigned short* hp = reinterpret_cast<const unsigned short*>(&c4);
            #pragma unroll
            for (int e = 0; e < 8; ++e)
                s += bf2f(hp[e]) * ts[kb * 8 + e];
        }
        vls[l] = s;
    } else if (wid == 5) {
        flg[l] = (seq[l * NB + b] > 0.f) ? 1 : 0;
    }
    __syncthreads();

    // ---- FULL denominator: thread t -> (n = t>>3, m = (t&7)*8 + j)
    {
        const int n = t >> 3;
        const int m0 = (t & 7) * 8;
        float a[8];
        int ok[8];
        const int fln = flg[n];
        int anyok = 0;
        #pragma unroll
        for (int j = 0; j < 8; ++j) {
            a[j] = PS[n * 64 + m0 + j];
            ok[j] = fln && flg[m0 + j] && (n != (m0 + j));
            anyok |= ok[j];
        }
        float s = 0.f;
        if (__any(anyok)) {
            for (int ll = 0; ll < 64; ++ll) {
                if (!flg[ll]) continue;        // wave-uniform skip
                float vv = vls[ll];
                #pragma unroll
                for (int j = 0; j < 8; ++j)
                    s += ok[j] ? __expf(a[j] * vv) : 0.f;
            }
            #pragma unroll
            for (int j = 0; j < 8; ++j)
                if (ok[j])
                    s -= __expf(a[j] * vls[n]) + __expf(a[j] * vls[m0 + j]);
        }
        #pragma unroll
        for (int off = 32; off > 0; off >>= 1) s += __shfl_down(s, off, 64);
        if (l == 0) wred[wid] = s;
        __syncthreads();
        if (t == 0) {
            sinv_s = 1.0f / (wred[0] + wred[1] + wred[2] + wred[3] +
                             wred[4] + wred[5] + wred[6] + wred[7]);
        }
    }
    __syncthreads();

    // ---- write output: this block's 32 slabs (n = nh*32 .. +31)
    const float inv = sinv_s;
    const int l0 = (l & 15) * 4;
    const float vv0 = vls[l0], vv1 = vls[l0 + 1], vv2 = vls[l0 + 2], vv3 = vls[l0 + 3];
    const int   fv0 = flg[l0], fv1 = flg[l0 + 1], fv2 = flg[l0 + 2], fv3 = flg[l0 + 3];

    #pragma unroll
    for (int s = 0; s < 4; ++s) {
        const int nl = wid * 4 + s;           // 0..31
        const int n  = nh * 32 + nl;
        float* slabp = out + ((size_t)b << 18) + ((size_t)n << 12);
        if (!flg[n]) {
            f32x4 z = {0.f, 0.f, 0.f, 0.f};
            #pragma unroll
            for (int it = 0; it < 16; ++it)
                __builtin_nontemporal_store(z,
                    reinterpret_cast<f32x4*>(slabp + it * 256 + (l >> 4) * 64 + l0));
            continue;
        }
        #pragma unroll
        for (int it = 0; it < 16; ++it) {
            const int m = it * 4 + (l >> 4);
            const float a = PS[n * 64 + m];
            const bool okm = flg[m] && (m != n);
            f32x4 o;
            o[0] = (okm && fv0 && (l0     != n) && (l0     != m)) ? __expf(a * vv0) * inv : 0.f;
            o[1] = (okm && fv1 && (l0 + 1 != n) && (l0 + 1 != m)) ? __expf(a * vv1) * inv : 0.f;
            o[2] = (okm && fv2 && (l0 + 2 != n) && (l0 + 2 != m)) ? __expf(a * vv2) * inv : 0.f;
            o[3] = (okm && fv3 && (l0 + 3 != n) && (l0 + 3 != m)) ? __expf(a * vv3) * inv : 0.f;
            __builtin_nontemporal_store(o,
                reinterpret_cast<f32x4*>(slabp + (size_t)m * 64 + l0));
        }
    }
}

// ---------------------------------------------------------------------------
extern "C" void kernel_launch(void* const* d_in, const int* in_sizes, int n_in,
                              void* d_out, int out_size, void* d_ws, size_t ws_size,
                              hipStream_t stream) {
    const float* x   = (const float*)d_in[0];
    const float* seq = (const float*)d_in[1];
    const float* W   = (const float*)d_in[2];
    char* wsb = (char*)d_ws;
    unsigned short* gpart = (unsigned short*)(wsb + WSB_GPART);
    unsigned short* Gh    = (unsigned short*)(wsb + WSB_GH);
    float*          tvec  = (float*)(wsb + WSB_T);
    float* out = (float*)d_out;

    k_gram <<<130, 1024, 0, stream>>>(W, gpart, tvec);
    k_gred <<<128, 256, 0, stream>>>(gpart, Gh);
    k_pvout<<<dim3(128, 2), 512, 0, stream>>>(x, Gh, tvec, seq, out);
}

// Round 11
// 49.627 us; speedup vs baseline: 2.5386x; 1.0603x over previous
//
#include <hip/hip_runtime.h>
#include <math.h>

#define NB 128     // BATCH

typedef short s16x8 __attribute__((ext_vector_type(8)));
typedef float f32x16 __attribute__((ext_vector_type(16)));
typedef float f32x4 __attribute__((ext_vector_type(4)));

// workspace layout (byte offsets)
#define WSB_GPART 0u                       // 128 chunks * 16384 bf16 = 4 MB
#define WSB_GH    4194304u                 // 16384 bf16 = 32 KB
#define WSB_T     4227072u                 // 128 fp32

static __device__ __forceinline__ unsigned short f2bf(float f) {
    unsigned int u = __float_as_uint(f);
    return (unsigned short)((u + 0x7fffu + ((u >> 16) & 1u)) >> 16);
}
static __device__ __forceinline__ float bf2f(unsigned short h) {
    return __uint_as_float(((unsigned int)h) << 16);
}

// ---------------------------------------------------------------------------
// Kernel 1: blocks 0..127: gram partials via MFMA (G = Wf Wf^T, Wf=(128,16384),
// chunk = 128 k-cols, 16 waves = all 16 32x32 tiles, W read once).
// Blocks 128..129: trace vector t[i] = sum_a W[i,a,a].
// ---------------------------------------------------------------------------
__global__ __launch_bounds__(1024) void k_gram(const float* __restrict__ W,
                                               unsigned short* __restrict__ gpart,
                                               float* __restrict__ tvec) {
    __shared__ char WS[32768];   // [128 rows][128 k] bf16, XOR-swizzled
    const int blk = blockIdx.x;
    const int t = threadIdx.x;   // 0..1023

    if (blk >= 128) {
        const int i = (blk - 128) * 64 + (t >> 4);
        const int a0 = (t & 15) * 8;
        float s = 0.f;
        #pragma unroll
        for (int a = a0; a < a0 + 8; ++a)
            s += W[(size_t)i * 16384 + a * 129];
        s += __shfl_down(s, 8, 16);
        s += __shfl_down(s, 4, 16);
        s += __shfl_down(s, 2, 16);
        s += __shfl_down(s, 1, 16);
        if ((t & 15) == 0) tvec[i] = s;
        return;
    }

    const int kc = blk;          // 0..127
    #pragma unroll
    for (int rep = 0; rep < 4; ++rep) {
        int ch = rep * 1024 + t;
        int row = ch >> 5, f4 = ch & 31;
        float4 w4 = *reinterpret_cast<const float4*>(
            W + (size_t)row * 16384 + kc * 128 + f4 * 4);
        ushort4 h = make_ushort4(f2bf(w4.x), f2bf(w4.y), f2bf(w4.z), f2bf(w4.w));
        *reinterpret_cast<ushort4*>(WS + row * 256 + ((f4 * 8) ^ ((row & 7) << 4))) = h;
    }
    __syncthreads();

    const int wid = t >> 6, l = t & 63;
    const int lr = l & 31, lhi = l >> 5;
    const int r = wid >> 2;              // output row-tile 0..3
    const int c = wid & 3;               // output col-tile 0..3

    f32x16 acc;
    #pragma unroll
    for (int i = 0; i < 16; ++i) acc[i] = 0.f;

    const int arow = r * 32 + lr;
    const int brow = c * 32 + lr;
    #pragma unroll
    for (int kk = 0; kk < 8; ++kk) {
        int kb = kk * 32 + lhi * 16;
        s16x8 a = *reinterpret_cast<const s16x8*>(WS + arow * 256 + (kb ^ ((arow & 7) << 4)));
        s16x8 bb = *reinterpret_cast<const s16x8*>(WS + brow * 256 + (kb ^ ((brow & 7) << 4)));
        acc = __builtin_amdgcn_mfma_f32_32x32x16_bf16(a, bb, acc, 0, 0, 0);
    }

    unsigned short* gp = gpart + (size_t)kc * 16384;
    #pragma unroll
    for (int reg = 0; reg < 16; ++reg) {
        int row = r * 32 + (reg & 3) + 8 * (reg >> 2) + 4 * lhi;
        gp[row * 128 + c * 32 + lr] = f2bf(acc[reg]);
    }
}

// ---------------------------------------------------------------------------
// Kernel 2: reduce bf16 partials -> Gh. Block owns 128 outputs; thread
// (og = t&15 -> 8 outputs, cg = t>>4 -> 8 chunks) does 8 independent uint4
// loads, then 2-stage LDS reduce.
// ---------------------------------------------------------------------------
__global__ __launch_bounds__(256) void k_gred(const unsigned short* __restrict__ gpart,
                                              unsigned short* __restrict__ Gh) {
    __shared__ float red[16 * 128];
    const int blk = blockIdx.x;      // 0..127
    const int t = threadIdx.x;       // 0..255
    const int og = t & 15;
    const int cg = t >> 4;

    float acc[8];
    #pragma unroll
    for (int e = 0; e < 8; ++e) acc[e] = 0.f;

    const unsigned short* base = gpart + blk * 128 + og * 8;
    #pragma unroll
    for (int c = 0; c < 8; ++c) {
        uint4 u = *reinterpret_cast<const uint4*>(base + (size_t)(cg * 8 + c) * 16384);
        const unsigned short* hp = reinterpret_cast<const unsigned short*>(&u);
        #pragma unroll
        for (int e = 0; e < 8; ++e) acc[e] += bf2f(hp[e]);
    }
    #pragma unroll
    for (int e = 0; e < 8; ++e) red[cg * 128 + og * 8 + e] = acc[e];
    __syncthreads();

    if (t < 128) {
        float s = 0.f;
        #pragma unroll
        for (int g = 0; g < 16; ++g) s += red[g * 128 + t];
        Gh[blk * 128 + t] = f2bf(s);
    }
}

// ---------------------------------------------------------------------------
// Kernel 3 (fused pv+den+out): block (b, nh), 1024 threads (16 waves).
//   Y = Xb G (8 tiles / waves 0-7, acc in regs), v (wave 8), flags (wave 9);
//   barrier; YS written into GS's first 16 KB (G is dead after Y's MFMAs);
//   P = (Y Xb^T)*scale (4 tiles / waves 0-3) -> PS; full denominator
//   (all 1024 threads, duplicated in both nh blocks); write 32 slabs with
//   16 waves (4 waves/SIMD in the store loop). LDS ~ 66 KiB.
// ---------------------------------------------------------------------------
__global__ __launch_bounds__(1024) void k_pvout(const float* __restrict__ x,
                                                const unsigned short* __restrict__ Gh,
                                                const float* __restrict__ tvec,
                                                const float* __restrict__ seq,
                                                float* __restrict__ out) {
    __shared__ char XS[16384];   // [64 jets][128] bf16 swz
    __shared__ char GS[32768];   // [128][128] bf16 swz; first 16 KB reused as YS
    __shared__ float PS[64 * 64];
    __shared__ float ts[128];
    __shared__ float vls[64];
    __shared__ int   flg[64];
    __shared__ float wred[16];
    __shared__ float sinv_s;
    char* YS = GS;               // alias: [64 rows][128] bf16 swz
    const int b  = blockIdx.x;   // 0..127
    const int nh = blockIdx.y;   // 0..1
    const int t = threadIdx.x;   // 0..1023

    // stage Xb: 2048 float4, 2/thread
    #pragma unroll
    for (int rep = 0; rep < 2; ++rep) {
        int ch = rep * 1024 + t;
        int row = ch >> 5, f4 = ch & 31;
        float4 x4 = *reinterpret_cast<const float4*>(
            x + (size_t)row * 16384 + b * 128 + f4 * 4);
        ushort4 h = make_ushort4(f2bf(x4.x), f2bf(x4.y), f2bf(x4.z), f2bf(x4.w));
        *reinterpret_cast<ushort4*>(XS + row * 256 + ((f4 * 8) ^ ((row & 7) << 4))) = h;
    }
    // stage Gh: 2048 16B chunks, 2/thread
    #pragma unroll
    for (int rep = 0; rep < 2; ++rep) {
        int ch = rep * 1024 + t;
        int row = ch >> 4, kb = ch & 15;
        uint4 g4 = *reinterpret_cast<const uint4*>(Gh + row * 128 + kb * 8);
        *reinterpret_cast<uint4*>(GS + row * 256 + ((kb * 16) ^ ((row & 7) << 4))) = g4;
    }
    if (t < 128) ts[t] = tvec[t];
    __syncthreads();

    const int wid = t >> 6, l = t & 63, lr = l & 31, lhi = l >> 5;

    // ---- Y: waves 0-7 compute tile (wid>>2, wid&3) into registers;
    //      wave 8: v; wave 9: flags
    f32x16 acc;
    if (wid < 8) {
        #pragma unroll
        for (int i = 0; i < 16; ++i) acc[i] = 0.f;
        const int arow = (wid >> 2) * 32 + lr;
        const int brow = (wid & 3) * 32 + lr;
        #pragma unroll
        for (int kk = 0; kk < 8; ++kk) {
            int kb = kk * 32 + lhi * 16;
            s16x8 a = *reinterpret_cast<const s16x8*>(XS + arow * 256 + (kb ^ ((arow & 7) << 4)));
            s16x8 g = *reinterpret_cast<const s16x8*>(GS + brow * 256 + (kb ^ ((brow & 7) << 4)));
            acc = __builtin_amdgcn_mfma_f32_32x32x16_bf16(a, g, acc, 0, 0, 0);
        }
    } else if (wid == 8) {
        float s = 0.f;
        #pragma unroll
        for (int kb = 0; kb < 16; ++kb) {
            uint4 c4 = *reinterpret_cast<const uint4*>(
                XS + l * 256 + ((kb * 16) ^ ((l & 7) << 4)));
            const unsigned short* hp = reinterpret_cast<const unsigned short*>(&c4);
            #pragma unroll
            for (int e = 0; e < 8; ++e)
                s += bf2f(hp[e]) * ts[kb * 8 + e];
        }
        vls[l] = s;
    } else if (wid == 9) {
        flg[l] = (seq[l * NB + b] > 0.f) ? 1 : 0;
    }
    __syncthreads();   // all GS reads done

    // ---- write Y (bf16) into YS (= GS first 16 KB)
    if (wid < 8) {
        #pragma unroll
        for (int reg = 0; reg < 16; ++reg) {
            int row = (wid >> 2) * 32 + (reg & 3) + 8 * (reg >> 2) + 4 * lhi;
            int col = (wid & 3) * 32 + lr;
            *reinterpret_cast<unsigned short*>(
                YS + row * 256 + ((2 * col) ^ ((row & 7) << 4))) = f2bf(acc[reg]);
        }
    }
    __syncthreads();

    // ---- full P (waves 0..3)
    if (wid < 4) {
        f32x16 pa;
        #pragma unroll
        for (int i = 0; i < 16; ++i) pa[i] = 0.f;
        const int arow = (wid >> 1) * 32 + lr;   // Y row (n)
        const int brow = (wid & 1) * 32 + lr;    // jet m
        #pragma unroll
        for (int kk = 0; kk < 8; ++kk) {
            int kb = kk * 32 + lhi * 16;
            s16x8 a = *reinterpret_cast<const s16x8*>(YS + arow * 256 + (kb ^ ((arow & 7) << 4)));
            s16x8 bb = *reinterpret_cast<const s16x8*>(XS + brow * 256 + (kb ^ ((brow & 7) << 4)));
            pa = __builtin_amdgcn_mfma_f32_32x32x16_bf16(a, bb, pa, 0, 0, 0);
        }
        const float SCALE = 1.0f / (128.0f * 128.0f * sqrtf(128.0f));
        #pragma unroll
        for (int reg = 0; reg < 16; ++reg) {
            int n = (wid >> 1) * 32 + (reg & 3) + 8 * (reg >> 2) + 4 * lhi;
            int m = (wid & 1) * 32 + lr;
            PS[n * 64 + m] = pa[reg] * SCALE;
        }
    }
    __syncthreads();

    // ---- FULL denominator: thread t -> (n = t>>4, m = (t&15)*4 + j)
    {
        const int n = t >> 4;
        const int m0 = (t & 15) * 4;
        float a[4];
        int ok[4];
        const int fln = flg[n];
        int anyok = 0;
        #pragma unroll
        for (int j = 0; j < 4; ++j) {
            a[j] = PS[n * 64 + m0 + j];
            ok[j] = fln && flg[m0 + j] && (n != (m0 + j));
            anyok |= ok[j];
        }
        float s = 0.f;
        if (__any(anyok)) {
            for (int ll = 0; ll < 64; ++ll) {
                if (!flg[ll]) continue;        // wave-uniform skip
                float vv = vls[ll];
                #pragma unroll
                for (int j = 0; j < 4; ++j)
                    s += ok[j] ? __expf(a[j] * vv) : 0.f;
            }
            #pragma unroll
            for (int j = 0; j < 4; ++j)
                if (ok[j])
                    s -= __expf(a[j] * vls[n]) + __expf(a[j] * vls[m0 + j]);
        }
        #pragma unroll
        for (int off = 32; off > 0; off >>= 1) s += __shfl_down(s, off, 64);
        if (l == 0) wred[wid] = s;
        __syncthreads();
        if (t == 0) {
            float tot = 0.f;
            #pragma unroll
            for (int w = 0; w < 16; ++w) tot += wred[w];
            sinv_s = 1.0f / tot;
        }
    }
    __syncthreads();

    // ---- write output: 32 slabs (n = nh*32 .. +31), 2 per wave
    const float inv = sinv_s;
    const int l0 = (l & 15) * 4;
    const float vv0 = vls[l0], vv1 = vls[l0 + 1], vv2 = vls[l0 + 2], vv3 = vls[l0 + 3];
    const int   fv0 = flg[l0], fv1 = flg[l0 + 1], fv2 = flg[l0 + 2], fv3 = flg[l0 + 3];

    #pragma unroll
    for (int s = 0; s < 2; ++s) {
        const int nl = wid * 2 + s;           // 0..31
        const int n  = nh * 32 + nl;
        float* slabp = out + ((size_t)b << 18) + ((size_t)n << 12);
        if (!flg[n]) {
            f32x4 z = {0.f, 0.f, 0.f, 0.f};
            #pragma unroll
            for (int it = 0; it < 16; ++it)
                __builtin_nontemporal_store(z,
                    reinterpret_cast<f32x4*>(slabp + it * 256 + (l >> 4) * 64 + l0));
            continue;
        }
        #pragma unroll
        for (int it = 0; it < 16; ++it) {
            const int m = it * 4 + (l >> 4);
            const float a = PS[n * 64 + m];
            const bool okm = flg[m] && (m != n);
            f32x4 o;
            o[0] = (okm && fv0 && (l0     != n) && (l0     != m)) ? __expf(a * vv0) * inv : 0.f;
            o[1] = (okm && fv1 && (l0 + 1 != n) && (l0 + 1 != m)) ? __expf(a * vv1) * inv : 0.f;
            o[2] = (okm && fv2 && (l0 + 2 != n) && (l0 + 2 != m)) ? __expf(a * vv2) * inv : 0.f;
            o[3] = (okm && fv3 && (l0 + 3 != n) && (l0 + 3 != m)) ? __expf(a * vv3) * inv : 0.f;
            __builtin_nontemporal_store(o,
                reinterpret_cast<f32x4*>(slabp + (size_t)m * 64 + l0));
        }
    }
}

// ---------------------------------------------------------------------------
extern "C" void kernel_launch(void* const* d_in, const int* in_sizes, int n_in,
                              void* d_out, int out_size, void* d_ws, size_t ws_size,
                              hipStream_t stream) {
    const float* x   = (const float*)d_in[0];
    const float* seq = (const float*)d_in[1];
    const float* W   = (const float*)d_in[2];
    char* wsb = (char*)d_ws;
    unsigned short* gpart = (unsigned short*)(wsb + WSB_GPART);
    unsigned short* Gh    = (unsigned short*)(wsb + WSB_GH);
    float*          tvec  = (float*)(wsb + WSB_T);
    float* out = (float*)d_out;

    k_gram <<<130, 1024, 0, stream>>>(W, gpart, tvec);
    k_gred <<<128, 256, 0, stream>>>(gpart, Gh);
    k_pvout<<<dim3(128, 2), 1024, 0, stream>>>(x, Gh, tvec, seq, out);
}